// Round 3
// baseline (619.489 us; speedup 1.0000x reference)
//
#include <hip/hip_runtime.h>
#include <hip/hip_bf16.h>

#define N_FULL 65536
#define NN1    16384
#define NN2    8192
#define KNN    16

// ---------------------------------------------------------------------------
// h0[n,c] = relu(x[n,:] @ W_down + b_down), x:[N,64] W:[64,32]
// block = 256 threads -> 8 rows x 32 cols
// ---------------------------------------------------------------------------
__global__ __launch_bounds__(256) void k_down(
    const float* __restrict__ x,
    const float* __restrict__ Wd,
    const float* __restrict__ bd,
    float* __restrict__ h0)
{
    __shared__ __align__(16) float Wl[64 * 32];
    __shared__ __align__(16) float xl[8 * 64];
    const int t = threadIdx.x;
    for (int i = t; i < 64 * 32; i += 256) Wl[i] = Wd[i];
    const int rowBase = blockIdx.x * 8;
    for (int i = t; i < 8 * 64; i += 256) xl[i] = x[(size_t)rowBase * 64 + i];
    __syncthreads();
    const int r = t >> 5, c = t & 31;
    float acc = bd[c];
#pragma unroll
    for (int i = 0; i < 64; ++i) acc += xl[r * 64 + i] * Wl[i * 32 + c];
    h0[(size_t)(rowBase + r) * 32 + c] = fmaxf(acc, 0.f);
}

// ---------------------------------------------------------------------------
// conv1: one wave (64 threads) per destination node d in [0,N1)
// lane l = output channel; fij channel l (l<32: h0[src], l>=32: rij)
// ---------------------------------------------------------------------------
__global__ __launch_bounds__(64) void k_conv1(
    const float* __restrict__ h0,
    const float* __restrict__ pos,
    const int* __restrict__ idx1,
    const int* __restrict__ src1,
    const float* __restrict__ Wpp, const float* __restrict__ bpp,
    const float* __restrict__ Watt, const float* __restrict__ batt,
    const float* __restrict__ Wg,  const float* __restrict__ bg,
    float* __restrict__ h1)
{
    const int d = blockIdx.x;
    const int l = threadIdx.x;

    // attention weight column l in registers: Watt[m, l]
    float wcol[64];
#pragma unroll
    for (int m = 0; m < 64; ++m) wcol[m] = Watt[m * 64 + l];
    const float battl = batt[l];

    const int pin = idx1[d];
    const float pix = pos[pin * 3 + 0];
    const float piy = pos[pin * 3 + 1];
    const float piz = pos[pin * 3 + 2];

    const int c = (l >= 32) ? (l - 32) : 0;
    float wpp[10];
#pragma unroll
    for (int i = 0; i < 10; ++i) wpp[i] = Wpp[i * 32 + c];
    const float bppl = bpp[c];

    float agg = 0.f;
    for (int e = 0; e < KNN; ++e) {
        const int s = src1[d * KNN + e];
        const float pjx = pos[s * 3 + 0];
        const float pjy = pos[s * 3 + 1];
        const float pjz = pos[s * 3 + 2];
        const float vx = pix - pjx, vy = piy - pjy, vz = piz - pjz;
        const float dij = sqrtf(vx * vx + vy * vy + vz * vz);

        float f;
        if (l < 32) {
            f = h0[(size_t)s * 32 + l];
        } else {
            // rel = [pos_i(3), pos_j(3), v(3), dij]
            float r = bppl;
            r += pix * wpp[0] + piy * wpp[1] + piz * wpp[2];
            r += pjx * wpp[3] + pjy * wpp[4] + pjz * wpp[5];
            r += vx * wpp[6] + vy * wpp[7] + vz * wpp[8];
            r += dij * wpp[9];
            f = fmaxf(r, 0.f);
        }

        // a_l = relu(sum_m f_m * Watt[m,l] + batt_l)
        float a = battl;
#pragma unroll
        for (int m = 0; m < 64; ++m) a += __shfl(f, m) * wcol[m];
        a = fmaxf(a, 0.f);

        // softmax over the 64 channels (cross-lane)
        float mx = a;
#pragma unroll
        for (int o = 32; o > 0; o >>= 1) mx = fmaxf(mx, __shfl_xor(mx, o));
        const float ex = __expf(a - mx);
        float sm = ex;
#pragma unroll
        for (int o = 32; o > 0; o >>= 1) sm += __shfl_xor(sm, o);

        agg += (ex / sm) * f;
    }

    // global_nn: out_l = relu(sum_m agg_m * Wg[m,l] + bg_l)
    float o = bg[l];
#pragma unroll
    for (int m = 0; m < 64; ++m) o += __shfl(agg, m) * Wg[m * 64 + l];
    h1[(size_t)d * 64 + l] = fmaxf(o, 0.f);
}

// ---------------------------------------------------------------------------
// conv2 + up/shortcut/final fused: 128 threads (2 waves) per destination node
// channel l: l<64 -> h1[src2], l>=64 -> rij
// ---------------------------------------------------------------------------
__global__ __launch_bounds__(128) void k_conv2f(
    const float* __restrict__ h1,
    const float* __restrict__ pos,
    const float* __restrict__ x,
    const int* __restrict__ idx1, const int* __restrict__ idx2,
    const int* __restrict__ src2,
    const float* __restrict__ Wpp, const float* __restrict__ bpp,
    const float* __restrict__ Watt, const float* __restrict__ batt,
    const float* __restrict__ Wg,  const float* __restrict__ bg,
    const float* __restrict__ Wup, const float* __restrict__ bup,
    const float* __restrict__ Wsc, const float* __restrict__ bsc,
    float* __restrict__ out)
{
    __shared__ __align__(16) float fls[128];
    __shared__ __align__(16) float xls[64];
    __shared__ float red[4];

    const int d = blockIdx.x;
    const int l = threadIdx.x;
    const int wv = l >> 6, lane = l & 63;

    float wcol[128];
#pragma unroll
    for (int m = 0; m < 128; ++m) wcol[m] = Watt[m * 128 + l];
    const float battl = batt[l];

    const int pin = idx1[idx2[d]];                 // pos2[d]'s node in full cloud
    if (l < 64) xls[l] = x[(size_t)pin * 64 + l];  // shortcut input row
    const float pix = pos[pin * 3 + 0];
    const float piy = pos[pin * 3 + 1];
    const float piz = pos[pin * 3 + 2];

    const int c = (l >= 64) ? (l - 64) : 0;
    float wpp[10];
#pragma unroll
    for (int i = 0; i < 10; ++i) wpp[i] = Wpp[i * 64 + c];
    const float bppl = bpp[c];

    float agg = 0.f;
    for (int e = 0; e < KNN; ++e) {
        const int s = src2[d * KNN + e];    // level-1 index
        const int sn = idx1[s];             // full-cloud node for position
        const float pjx = pos[sn * 3 + 0];
        const float pjy = pos[sn * 3 + 1];
        const float pjz = pos[sn * 3 + 2];
        const float vx = pix - pjx, vy = piy - pjy, vz = piz - pjz;
        const float dij = sqrtf(vx * vx + vy * vy + vz * vz);

        float f;
        if (l < 64) {
            f = h1[(size_t)s * 64 + l];
        } else {
            float r = bppl;
            r += pix * wpp[0] + piy * wpp[1] + piz * wpp[2];
            r += pjx * wpp[3] + pjy * wpp[4] + pjz * wpp[5];
            r += vx * wpp[6] + vy * wpp[7] + vz * wpp[8];
            r += dij * wpp[9];
            f = fmaxf(r, 0.f);
        }

        fls[l] = f;
        __syncthreads();

        float a = battl;
#pragma unroll
        for (int m = 0; m < 128; m += 4) {
            const float4 fv = *reinterpret_cast<const float4*>(&fls[m]);
            a += fv.x * wcol[m + 0] + fv.y * wcol[m + 1]
               + fv.z * wcol[m + 2] + fv.w * wcol[m + 3];
        }
        a = fmaxf(a, 0.f);

        // softmax over 128 channels: wave reduce + cross-wave via LDS
        float mx = a;
#pragma unroll
        for (int o = 32; o > 0; o >>= 1) mx = fmaxf(mx, __shfl_xor(mx, o));
        if (lane == 0) red[wv] = mx;
        __syncthreads();
        mx = fmaxf(red[0], red[1]);

        const float ex = __expf(a - mx);
        float sm = ex;
#pragma unroll
        for (int o = 32; o > 0; o >>= 1) sm += __shfl_xor(sm, o);
        if (lane == 0) red[2 + wv] = sm;
        __syncthreads();
        sm = red[2] + red[3];

        agg += (ex / sm) * f;
        __syncthreads();                 // protect fls/red for next edge
    }

    // global_nn -> h2 channel l
    fls[l] = agg;
    __syncthreads();
    float o = bg[l];
#pragma unroll
    for (int m = 0; m < 128; m += 4) {
        const float4 av = *reinterpret_cast<const float4*>(&fls[m]);
        o += av.x * Wg[(m + 0) * 128 + l] + av.y * Wg[(m + 1) * 128 + l]
           + av.z * Wg[(m + 2) * 128 + l] + av.w * Wg[(m + 3) * 128 + l];
    }
    o = fmaxf(o, 0.f);

    // up-projection needs all 128 h2 values
    __syncthreads();
    fls[l] = o;
    __syncthreads();
    float u = bup[l];
#pragma unroll
    for (int m = 0; m < 128; m += 4) {
        const float4 hv = *reinterpret_cast<const float4*>(&fls[m]);
        u += hv.x * Wup[(m + 0) * 128 + l] + hv.y * Wup[(m + 1) * 128 + l]
           + hv.z * Wup[(m + 2) * 128 + l] + hv.w * Wup[(m + 3) * 128 + l];
    }
    u = fmaxf(u, 0.f);

    // shortcut: relu(x[pin,:] @ Wsc + bsc)
    float sc = bsc[l];
#pragma unroll
    for (int m = 0; m < 64; m += 4) {
        const float4 xv = *reinterpret_cast<const float4*>(&xls[m]);
        sc += xv.x * Wsc[(m + 0) * 128 + l] + xv.y * Wsc[(m + 1) * 128 + l]
            + xv.z * Wsc[(m + 2) * 128 + l] + xv.w * Wsc[(m + 3) * 128 + l];
    }
    sc = fmaxf(sc, 0.f);

    out[(size_t)d * 128 + l] = fmaxf(u + sc, 0.f);
}

extern "C" void kernel_launch(void* const* d_in, const int* in_sizes, int n_in,
                              void* d_out, int out_size, void* d_ws, size_t ws_size,
                              hipStream_t stream)
{
    const float* x      = (const float*)d_in[0];
    const float* pos    = (const float*)d_in[1];
    const float* W_down = (const float*)d_in[2];
    const float* b_down = (const float*)d_in[3];
    const float* W_pp1  = (const float*)d_in[4];
    const float* b_pp1  = (const float*)d_in[5];
    const float* W_att1 = (const float*)d_in[6];
    const float* b_att1 = (const float*)d_in[7];
    const float* W_g1   = (const float*)d_in[8];
    const float* b_g1   = (const float*)d_in[9];
    const float* W_pp2  = (const float*)d_in[10];
    const float* b_pp2  = (const float*)d_in[11];
    const float* W_att2 = (const float*)d_in[12];
    const float* b_att2 = (const float*)d_in[13];
    const float* W_g2   = (const float*)d_in[14];
    const float* b_g2   = (const float*)d_in[15];
    const float* W_up   = (const float*)d_in[16];
    const float* b_up   = (const float*)d_in[17];
    const float* W_sc   = (const float*)d_in[18];
    const float* b_sc   = (const float*)d_in[19];
    const int* idx1 = (const int*)d_in[20];
    const int* idx2 = (const int*)d_in[21];
    const int* src1 = (const int*)d_in[22];
    /* d_in[23] = dst1 (repeat(arange(N1),16)) — implicit */
    const int* src2 = (const int*)d_in[24];
    /* d_in[25] = dst2 — implicit */

    // ws layout: h0 fp32 [N,32] | h1 fp32 [N1,64]  = 12 MB
    float* h0 = (float*)d_ws;
    float* h1 = h0 + (size_t)N_FULL * 32;

    k_down  <<<N_FULL / 8, 256, 0, stream>>>(x, W_down, b_down, h0);
    k_conv1 <<<NN1, 64, 0, stream>>>(h0, pos, idx1, src1,
                                     W_pp1, b_pp1, W_att1, b_att1, W_g1, b_g1, h1);
    k_conv2f<<<NN2, 128, 0, stream>>>(h1, pos, x, idx1, idx2, src2,
                                      W_pp2, b_pp2, W_att2, b_att2, W_g2, b_g2,
                                      W_up, b_up, W_sc, b_sc, (float*)d_out);
}

// Round 4
// 406.840 us; speedup vs baseline: 1.5227x; 1.5227x over previous
//
#include <hip/hip_runtime.h>

#define N_FULL 65536
#define NN1    16384
#define NN2    8192
#define KNN    16

// ---------------------------------------------------------------------------
// h0[n,c] = relu(x[n,:] @ W_down + b_down), x:[N,64] W:[64,32]
// ---------------------------------------------------------------------------
__global__ __launch_bounds__(256) void k_down(
    const float* __restrict__ x,
    const float* __restrict__ Wd,
    const float* __restrict__ bd,
    float* __restrict__ h0)
{
    __shared__ __align__(16) float Wl[64 * 32];
    __shared__ __align__(16) float xl[8 * 64];
    const int t = threadIdx.x;
    for (int i = t; i < 64 * 32; i += 256) Wl[i] = Wd[i];
    const int rowBase = blockIdx.x * 8;
    for (int i = t; i < 8 * 64; i += 256) xl[i] = x[(size_t)rowBase * 64 + i];
    __syncthreads();
    const int r = t >> 5, c = t & 31;
    float acc = bd[c];
#pragma unroll
    for (int i = 0; i < 64; ++i) acc += xl[r * 64 + i] * Wl[i * 32 + c];
    h0[(size_t)(rowBase + r) * 32 + c] = fmaxf(acc, 0.f);
}

// ---------------------------------------------------------------------------
// conv1: block = 256 threads = 8 nodes x 16 edges. fij [128 edges][64 ch] in
// LDS (stride 68 -> 2-way bank aliasing only). Attention: thread=(edge-group,
// channel); weights coalesced from global, shared across 32 edges in regs.
// ---------------------------------------------------------------------------
__global__ __launch_bounds__(256) void k_conv1(
    const float* __restrict__ h0,
    const float* __restrict__ pos,
    const int* __restrict__ idx1,
    const int* __restrict__ src1,
    const float* __restrict__ Wpp, const float* __restrict__ bpp,
    const float* __restrict__ Watt, const float* __restrict__ batt,
    const float* __restrict__ Wg,  const float* __restrict__ bg,
    float* __restrict__ h1)
{
    constexpr int G = 8, FSTR = 68;
    __shared__ __align__(16) float fij[128 * FSTR];   // 34.8 KB
    __shared__ __align__(16) float aggls[G * 64];     // 2 KB

    const int t = threadIdx.x;
    const int d0 = blockIdx.x * G;

    // ---- fill fij: 2 threads per edge ----
    {
        const int e = t >> 1, half = t & 1;
        const int g = e >> 4;
        const int pin = idx1[d0 + g];
        const float pix = pos[pin * 3 + 0];
        const float piy = pos[pin * 3 + 1];
        const float piz = pos[pin * 3 + 2];
        const int s = src1[(d0 + g) * KNN + (e & 15)];
        float* frow = &fij[e * FSTR];
        if (half == 0) {
            const float* hr = &h0[(size_t)s * 32];
#pragma unroll
            for (int j = 0; j < 32; j += 4)
                *reinterpret_cast<float4*>(frow + j) =
                    *reinterpret_cast<const float4*>(hr + j);
        } else {
            const float pjx = pos[s * 3 + 0];
            const float pjy = pos[s * 3 + 1];
            const float pjz = pos[s * 3 + 2];
            const float vx = pix - pjx, vy = piy - pjy, vz = piz - pjz;
            const float dij = sqrtf(vx * vx + vy * vy + vz * vz);
            const float rel[10] = {pix, piy, piz, pjx, pjy, pjz, vx, vy, vz, dij};
#pragma unroll
            for (int c = 0; c < 32; c += 4) {
                float4 r;
                float* rp = &r.x;
#pragma unroll
                for (int q = 0; q < 4; ++q) {
                    float acc = bpp[c + q];
#pragma unroll
                    for (int i = 0; i < 10; ++i) acc += rel[i] * Wpp[i * 32 + c + q];
                    rp[q] = fmaxf(acc, 0.f);
                }
                *reinterpret_cast<float4*>(frow + 32 + c) = r;
            }
        }
    }
    __syncthreads();

    // ---- attention + softmax + aggregate ----
    {
        const int l = t & 63, eh = t >> 6;      // edges eh*32 .. eh*32+31
        const int e0 = eh * 32;
        const float battl = batt[l];
        float acc[32];
#pragma unroll
        for (int e = 0; e < 32; ++e) acc[e] = battl;
        for (int m = 0; m < 64; m += 4) {
            const float w0 = Watt[(m + 0) * 64 + l];
            const float w1 = Watt[(m + 1) * 64 + l];
            const float w2 = Watt[(m + 2) * 64 + l];
            const float w3 = Watt[(m + 3) * 64 + l];
#pragma unroll
            for (int e = 0; e < 32; ++e) {
                const float4 f = *reinterpret_cast<const float4*>(&fij[(e0 + e) * FSTR + m]);
                acc[e] = fmaf(f.x, w0, fmaf(f.y, w1, fmaf(f.z, w2, fmaf(f.w, w3, acc[e]))));
            }
        }
        float agg0 = 0.f, agg1 = 0.f;           // nodes eh*2, eh*2+1
#pragma unroll
        for (int e = 0; e < 32; ++e) {
            const float a = fmaxf(acc[e], 0.f);
            float mx = a;
#pragma unroll
            for (int o = 32; o > 0; o >>= 1) mx = fmaxf(mx, __shfl_xor(mx, o));
            const float ex = __expf(a - mx);
            float sm = ex;
#pragma unroll
            for (int o = 32; o > 0; o >>= 1) sm += __shfl_xor(sm, o);
            const float contrib = (ex / sm) * fij[(e0 + e) * FSTR + l];
            if (e < 16) agg0 += contrib; else agg1 += contrib;
        }
        aggls[(eh * 2 + 0) * 64 + l] = agg0;
        aggls[(eh * 2 + 1) * 64 + l] = agg1;
    }
    __syncthreads();

    // ---- global_nn ----
    {
        const int l = t & 63, gh = t >> 6;      // nodes gh*2, gh*2+1
        const float bgl = bg[l];
        float a0 = bgl, a1 = bgl;
        for (int m = 0; m < 64; m += 4) {
            const float w0 = Wg[(m + 0) * 64 + l];
            const float w1 = Wg[(m + 1) * 64 + l];
            const float w2 = Wg[(m + 2) * 64 + l];
            const float w3 = Wg[(m + 3) * 64 + l];
            const float4 q0 = *reinterpret_cast<const float4*>(&aggls[(gh * 2 + 0) * 64 + m]);
            const float4 q1 = *reinterpret_cast<const float4*>(&aggls[(gh * 2 + 1) * 64 + m]);
            a0 += q0.x * w0 + q0.y * w1 + q0.z * w2 + q0.w * w3;
            a1 += q1.x * w0 + q1.y * w1 + q1.z * w2 + q1.w * w3;
        }
        h1[(size_t)(d0 + gh * 2 + 0) * 64 + l] = fmaxf(a0, 0.f);
        h1[(size_t)(d0 + gh * 2 + 1) * 64 + l] = fmaxf(a1, 0.f);
    }
}

// ---------------------------------------------------------------------------
// conv2 + up/shortcut/final: block = 256 threads = 4 nodes x 16 edges.
// fij [64 edges][128 ch] LDS stride 132. Softmax spans 2 waves -> LDS combine.
// ---------------------------------------------------------------------------
__global__ __launch_bounds__(256) void k_conv2f(
    const float* __restrict__ h1,
    const float* __restrict__ pos,
    const float* __restrict__ x,
    const int* __restrict__ idx1, const int* __restrict__ idx2,
    const int* __restrict__ src2,
    const float* __restrict__ Wpp, const float* __restrict__ bpp,
    const float* __restrict__ Watt, const float* __restrict__ batt,
    const float* __restrict__ Wg,  const float* __restrict__ bg,
    const float* __restrict__ Wup, const float* __restrict__ bup,
    const float* __restrict__ Wsc, const float* __restrict__ bsc,
    float* __restrict__ out)
{
    constexpr int G = 4, FSTR = 132;
    __shared__ __align__(16) float fij[64 * FSTR];    // 33.8 KB
    __shared__ __align__(16) float aggls[G * 128];    // 2 KB
    __shared__ __align__(16) float h2ls[G * 128];     // 2 KB
    __shared__ __align__(16) float xls[G * 64];       // 1 KB
    __shared__ float redmax[4][32];
    __shared__ float redsum[4][32];

    const int t = threadIdx.x;
    const int d0 = blockIdx.x * G;

    // ---- fill fij + shortcut rows ----
    {
        const int e = t >> 2, q = t & 3;        // 64 edges x 4 threads
        const int g = e >> 4;
        const int pin = idx1[idx2[d0 + g]];
        const float pix = pos[pin * 3 + 0];
        const float piy = pos[pin * 3 + 1];
        const float piz = pos[pin * 3 + 2];
        const int s = src2[(d0 + g) * KNN + (e & 15)];
        float* frow = &fij[e * FSTR];
        if (q < 2) {
            const float* hr = &h1[(size_t)s * 64 + q * 32];
#pragma unroll
            for (int j = 0; j < 32; j += 4)
                *reinterpret_cast<float4*>(frow + q * 32 + j) =
                    *reinterpret_cast<const float4*>(hr + j);
        } else {
            const int sn = idx1[s];
            const float pjx = pos[sn * 3 + 0];
            const float pjy = pos[sn * 3 + 1];
            const float pjz = pos[sn * 3 + 2];
            const float vx = pix - pjx, vy = piy - pjy, vz = piz - pjz;
            const float dij = sqrtf(vx * vx + vy * vy + vz * vz);
            const float rel[10] = {pix, piy, piz, pjx, pjy, pjz, vx, vy, vz, dij};
            const int c0 = (q - 2) * 32;
#pragma unroll
            for (int c = 0; c < 32; c += 4) {
                float4 r;
                float* rp = &r.x;
#pragma unroll
                for (int qq = 0; qq < 4; ++qq) {
                    float acc = bpp[c0 + c + qq];
#pragma unroll
                    for (int i = 0; i < 10; ++i) acc += rel[i] * Wpp[i * 64 + c0 + c + qq];
                    rp[qq] = fmaxf(acc, 0.f);
                }
                *reinterpret_cast<float4*>(frow + 64 + c0 + c) = r;
            }
        }
        // shortcut input rows: 1 value / thread
        const int gx = t >> 6, cx = t & 63;
        const int pinx = idx1[idx2[d0 + gx]];
        xls[gx * 64 + cx] = x[(size_t)pinx * 64 + cx];
    }
    __syncthreads();

    const int l = t & 127, eh = t >> 7;          // edges eh*32 .. +31
    const int e0 = eh * 32;
    const int w = t >> 6;                         // wave id 0..3
    const int lane = t & 63;

    // ---- attention matvec ----
    float acc[32];
    {
        const float battl = batt[l];
#pragma unroll
        for (int e = 0; e < 32; ++e) acc[e] = battl;
        for (int m = 0; m < 128; m += 4) {
            const float w0 = Watt[(m + 0) * 128 + l];
            const float w1 = Watt[(m + 1) * 128 + l];
            const float w2 = Watt[(m + 2) * 128 + l];
            const float w3 = Watt[(m + 3) * 128 + l];
#pragma unroll
            for (int e = 0; e < 32; ++e) {
                const float4 f = *reinterpret_cast<const float4*>(&fij[(e0 + e) * FSTR + m]);
                acc[e] = fmaf(f.x, w0, fmaf(f.y, w1, fmaf(f.z, w2, fmaf(f.w, w3, acc[e]))));
            }
        }
    }
    // pass 1: relu + wave-partial max
#pragma unroll
    for (int e = 0; e < 32; ++e) {
        const float a = fmaxf(acc[e], 0.f);
        acc[e] = a;
        float mx = a;
#pragma unroll
        for (int o = 32; o > 0; o >>= 1) mx = fmaxf(mx, __shfl_xor(mx, o));
        if (lane == 0) redmax[w][e] = mx;
    }
    __syncthreads();
    // pass 2: exp + wave-partial sum
#pragma unroll
    for (int e = 0; e < 32; ++e) {
        const float mx = fmaxf(redmax[eh * 2 + 0][e], redmax[eh * 2 + 1][e]);
        const float ex = __expf(acc[e] - mx);
        acc[e] = ex;
        float sm = ex;
#pragma unroll
        for (int o = 32; o > 0; o >>= 1) sm += __shfl_xor(sm, o);
        if (lane == 0) redsum[w][e] = sm;
    }
    __syncthreads();
    // pass 3: scale + aggregate (nodes eh*2, eh*2+1)
    {
        float agg0 = 0.f, agg1 = 0.f;
#pragma unroll
        for (int e = 0; e < 32; ++e) {
            const float sm = redsum[eh * 2 + 0][e] + redsum[eh * 2 + 1][e];
            const float contrib = (acc[e] / sm) * fij[(e0 + e) * FSTR + l];
            if (e < 16) agg0 += contrib; else agg1 += contrib;
        }
        aggls[(eh * 2 + 0) * 128 + l] = agg0;
        aggls[(eh * 2 + 1) * 128 + l] = agg1;
    }
    __syncthreads();

    // ---- global_nn: h2 (nodes eh*2, eh*2+1) ----
    {
        const float bgl = bg[l];
        float a0 = bgl, a1 = bgl;
        for (int m = 0; m < 128; m += 4) {
            const float w0 = Wg[(m + 0) * 128 + l];
            const float w1 = Wg[(m + 1) * 128 + l];
            const float w2 = Wg[(m + 2) * 128 + l];
            const float w3 = Wg[(m + 3) * 128 + l];
            const float4 q0 = *reinterpret_cast<const float4*>(&aggls[(eh * 2 + 0) * 128 + m]);
            const float4 q1 = *reinterpret_cast<const float4*>(&aggls[(eh * 2 + 1) * 128 + m]);
            a0 += q0.x * w0 + q0.y * w1 + q0.z * w2 + q0.w * w3;
            a1 += q1.x * w0 + q1.y * w1 + q1.z * w2 + q1.w * w3;
        }
        h2ls[(eh * 2 + 0) * 128 + l] = fmaxf(a0, 0.f);
        h2ls[(eh * 2 + 1) * 128 + l] = fmaxf(a1, 0.f);
    }
    __syncthreads();

    // ---- up + shortcut + final ----
    {
        const float bupl = bup[l];
        float u0 = bupl, u1 = bupl;
        for (int m = 0; m < 128; m += 4) {
            const float w0 = Wup[(m + 0) * 128 + l];
            const float w1 = Wup[(m + 1) * 128 + l];
            const float w2 = Wup[(m + 2) * 128 + l];
            const float w3 = Wup[(m + 3) * 128 + l];
            const float4 q0 = *reinterpret_cast<const float4*>(&h2ls[(eh * 2 + 0) * 128 + m]);
            const float4 q1 = *reinterpret_cast<const float4*>(&h2ls[(eh * 2 + 1) * 128 + m]);
            u0 += q0.x * w0 + q0.y * w1 + q0.z * w2 + q0.w * w3;
            u1 += q1.x * w0 + q1.y * w1 + q1.z * w2 + q1.w * w3;
        }
        const float bscl = bsc[l];
        float s0 = bscl, s1 = bscl;
        for (int m = 0; m < 64; m += 4) {
            const float w0 = Wsc[(m + 0) * 128 + l];
            const float w1 = Wsc[(m + 1) * 128 + l];
            const float w2 = Wsc[(m + 2) * 128 + l];
            const float w3 = Wsc[(m + 3) * 128 + l];
            const float4 q0 = *reinterpret_cast<const float4*>(&xls[(eh * 2 + 0) * 64 + m]);
            const float4 q1 = *reinterpret_cast<const float4*>(&xls[(eh * 2 + 1) * 64 + m]);
            s0 += q0.x * w0 + q0.y * w1 + q0.z * w2 + q0.w * w3;
            s1 += q1.x * w0 + q1.y * w1 + q1.z * w2 + q1.w * w3;
        }
        out[(size_t)(d0 + eh * 2 + 0) * 128 + l] = fmaxf(fmaxf(u0, 0.f) + fmaxf(s0, 0.f), 0.f);
        out[(size_t)(d0 + eh * 2 + 1) * 128 + l] = fmaxf(fmaxf(u1, 0.f) + fmaxf(s1, 0.f), 0.f);
    }
}

extern "C" void kernel_launch(void* const* d_in, const int* in_sizes, int n_in,
                              void* d_out, int out_size, void* d_ws, size_t ws_size,
                              hipStream_t stream)
{
    const float* x      = (const float*)d_in[0];
    const float* pos    = (const float*)d_in[1];
    const float* W_down = (const float*)d_in[2];
    const float* b_down = (const float*)d_in[3];
    const float* W_pp1  = (const float*)d_in[4];
    const float* b_pp1  = (const float*)d_in[5];
    const float* W_att1 = (const float*)d_in[6];
    const float* b_att1 = (const float*)d_in[7];
    const float* W_g1   = (const float*)d_in[8];
    const float* b_g1   = (const float*)d_in[9];
    const float* W_pp2  = (const float*)d_in[10];
    const float* b_pp2  = (const float*)d_in[11];
    const float* W_att2 = (const float*)d_in[12];
    const float* b_att2 = (const float*)d_in[13];
    const float* W_g2   = (const float*)d_in[14];
    const float* b_g2   = (const float*)d_in[15];
    const float* W_up   = (const float*)d_in[16];
    const float* b_up   = (const float*)d_in[17];
    const float* W_sc   = (const float*)d_in[18];
    const float* b_sc   = (const float*)d_in[19];
    const int* idx1 = (const int*)d_in[20];
    const int* idx2 = (const int*)d_in[21];
    const int* src1 = (const int*)d_in[22];
    const int* src2 = (const int*)d_in[24];

    // ws: h0 fp32 [N,32] | h1 fp32 [N1,64]
    float* h0 = (float*)d_ws;
    float* h1 = h0 + (size_t)N_FULL * 32;

    k_down  <<<N_FULL / 8, 256, 0, stream>>>(x, W_down, b_down, h0);
    k_conv1 <<<NN1 / 8, 256, 0, stream>>>(h0, pos, idx1, src1,
                                          W_pp1, b_pp1, W_att1, b_att1, W_g1, b_g1, h1);
    k_conv2f<<<NN2 / 4, 256, 0, stream>>>(h1, pos, x, idx1, idx2, src2,
                                          W_pp2, b_pp2, W_att2, b_att2, W_g2, b_g2,
                                          W_up, b_up, W_sc, b_sc, (float*)d_out);
}

// Round 5
// 202.985 us; speedup vs baseline: 3.0519x; 2.0043x over previous
//
#include <hip/hip_runtime.h>

#define N_FULL 65536
#define NN1    16384
#define NN2    8192

typedef __attribute__((ext_vector_type(8))) short bf16x8;
typedef __attribute__((ext_vector_type(4))) float f32x4;
typedef unsigned short ushortT;

#define MFMA16(acc, a, b) acc = __builtin_amdgcn_mfma_f32_16x16x32_bf16(a, b, acc, 0, 0, 0)

static __device__ __forceinline__ ushortT f2bf(float f) {
    union { float f; unsigned u; } v; v.f = f;
    unsigned r = v.u + 0x7FFFu + ((v.u >> 16) & 1u);
    return (ushortT)(r >> 16);
}
static __device__ __forceinline__ unsigned pack2(float a, float b) {
    return (unsigned)f2bf(a) | ((unsigned)f2bf(b) << 16);
}
static __device__ __forceinline__ float bfu2f(ushortT h) {
    union { unsigned u; float f; } v; v.u = (unsigned)h << 16; return v.f;
}

// ws layout (ushort units)
#define WS_WDT   0        /* [32][72]   */
#define WS_WAT1  2304     /* [64][72]   */
#define WS_WGT1  6912     /* [64][72]   */
#define WS_WAT2  11520    /* [128][136] */
#define WS_WGT2  28928    /* [128][136] */
#define WS_WUPT  46336    /* [128][136] */
#define WS_WSCT  63744    /* [128][72]  */
#define WS_H0    73728    /* bf16 [65536][32] */
#define WS_H1    (WS_H0 + 65536u*32u)
#define WS_AGG1  (WS_H1 + 16384u*64u)
#define WS_AGG2  (WS_AGG1 + 16384u*64u)

// ---------------------------------------------------------------------------
// k_prep: transpose weights to [n][k] bf16 with padded row stride
// ---------------------------------------------------------------------------
static __device__ __forceinline__ void tpose(
    const float* __restrict__ src, ushortT* __restrict__ dst,
    int K, int N, int STR, int gid, int gs)
{
    for (int i = gid; i < K * N; i += gs) {
        const int n = i / K, k = i - n * K;
        dst[n * STR + k] = f2bf(src[(size_t)k * N + n]);
    }
}

__global__ __launch_bounds__(256) void k_prep(
    const float* __restrict__ Wd, const float* __restrict__ Wa1,
    const float* __restrict__ Wg1, const float* __restrict__ Wa2,
    const float* __restrict__ Wg2, const float* __restrict__ Wup,
    const float* __restrict__ Wsc, ushortT* __restrict__ wsw)
{
    const int gid = blockIdx.x * 256 + threadIdx.x, gs = gridDim.x * 256;
    tpose(Wd,  wsw + WS_WDT,  64, 32, 72,  gid, gs);
    tpose(Wa1, wsw + WS_WAT1, 64, 64, 72,  gid, gs);
    tpose(Wg1, wsw + WS_WGT1, 64, 64, 72,  gid, gs);
    tpose(Wa2, wsw + WS_WAT2, 128, 128, 136, gid, gs);
    tpose(Wg2, wsw + WS_WGT2, 128, 128, 136, gid, gs);
    tpose(Wup, wsw + WS_WUPT, 128, 128, 136, gid, gs);
    tpose(Wsc, wsw + WS_WSCT, 64, 128, 72, gid, gs);
}

// ---------------------------------------------------------------------------
// k_down: h0 = relu(x @ Wd + bd) bf16, MFMA. 128 rows/block.
// ---------------------------------------------------------------------------
__global__ __launch_bounds__(256) void k_down(
    const float* __restrict__ x, const ushortT* __restrict__ wsw,
    const float* __restrict__ bd, ushortT* __restrict__ h0w)
{
    __shared__ ushortT Al[128 * 72];
    __shared__ ushortT Bl[32 * 72];
    const int t = threadIdx.x;
    const int rowBase = blockIdx.x * 128;

    {   // stage A: x rows -> bf16 LDS
        const int r = t >> 1, c0 = (t & 1) * 32;
        unsigned* dst = (unsigned*)Al + r * 36 + (c0 >> 1);
        const float* src = &x[(size_t)(rowBase + r) * 64 + c0];
#pragma unroll
        for (int j = 0; j < 32; j += 4) {
            const float4 v = *reinterpret_cast<const float4*>(src + j);
            dst[(j >> 1) + 0] = pack2(v.x, v.y);
            dst[(j >> 1) + 1] = pack2(v.z, v.w);
        }
        const unsigned* wsrc = (const unsigned*)(wsw + WS_WDT);
        for (int i = t; i < 1152; i += 256) ((unsigned*)Bl)[i] = wsrc[i];
    }
    __syncthreads();

    const int lane = t & 63, w = t >> 6, quad = lane >> 4, c16 = lane & 15;
    f32x4 acc[2][2];
#pragma unroll
    for (int mt = 0; mt < 2; ++mt)
#pragma unroll
        for (int nt = 0; nt < 2; ++nt)
#pragma unroll
            for (int r = 0; r < 4; ++r) acc[mt][nt][r] = 0.f;
#pragma unroll
    for (int ks = 0; ks < 2; ++ks) {
        bf16x8 a[2], b[2];
#pragma unroll
        for (int mt = 0; mt < 2; ++mt)
            a[mt] = *(const bf16x8*)&Al[(w * 32 + mt * 16 + c16) * 72 + ks * 32 + quad * 8];
#pragma unroll
        for (int nt = 0; nt < 2; ++nt)
            b[nt] = *(const bf16x8*)&Bl[(nt * 16 + c16) * 72 + ks * 32 + quad * 8];
#pragma unroll
        for (int mt = 0; mt < 2; ++mt)
#pragma unroll
            for (int nt = 0; nt < 2; ++nt) MFMA16(acc[mt][nt], a[mt], b[nt]);
    }
#pragma unroll
    for (int nt = 0; nt < 2; ++nt) {
        const int col = nt * 16 + c16;
        const float bias = bd[col];
#pragma unroll
        for (int mt = 0; mt < 2; ++mt)
#pragma unroll
            for (int r = 0; r < 4; ++r) {
                const int row = rowBase + w * 32 + mt * 16 + quad * 4 + r;
                h0w[(size_t)row * 32 + col] = f2bf(fmaxf(acc[mt][nt][r] + bias, 0.f));
            }
    }
}

// ---------------------------------------------------------------------------
// k_conv1: 8 nodes/block, F=[128 edges][64 ch] bf16, MFMA attention +
// in-wave softmax + per-tile aggregate -> agg1 bf16
// ---------------------------------------------------------------------------
__global__ __launch_bounds__(256) void k_conv1(
    const ushortT* __restrict__ h0w, const float* __restrict__ pos,
    const int* __restrict__ idx1, const int* __restrict__ src1,
    const float* __restrict__ Wpp, const float* __restrict__ bpp,
    const ushortT* __restrict__ wsw, const float* __restrict__ batt,
    ushortT* __restrict__ agg1w)
{
    __shared__ ushortT Fl[128 * 72];
    __shared__ ushortT Wl[64 * 72];
    __shared__ float Pl[352];          // Wpp1 [10][32] + bpp1[32]
    const int t = threadIdx.x;
    const int d0 = blockIdx.x * 8;

    {   // stage Watt^T + pp weights
        const unsigned* wsrc = (const unsigned*)(wsw + WS_WAT1);
        for (int i = t; i < 2304; i += 256) ((unsigned*)Wl)[i] = wsrc[i];
        for (int i = t; i < 352; i += 256) Pl[i] = (i < 320) ? Wpp[i] : bpp[i - 320];
    }
    __syncthreads();

    {   // build F: 2 threads/edge
        const int e = t >> 1, half = t & 1;
        const int g = e >> 4;
        const int s = src1[(d0 + g) * 16 + (e & 15)];
        const unsigned* srcp = (const unsigned*)h0w + (size_t)s * 16 + half * 8;
        unsigned* dstp = (unsigned*)Fl + e * 36 + half * 8;
#pragma unroll
        for (int j = 0; j < 8; ++j) dstp[j] = srcp[j];

        const int pin = idx1[d0 + g];
        const float pix = pos[pin * 3 + 0], piy = pos[pin * 3 + 1], piz = pos[pin * 3 + 2];
        const float pjx = pos[s * 3 + 0],  pjy = pos[s * 3 + 1],  pjz = pos[s * 3 + 2];
        const float vx = pix - pjx, vy = piy - pjy, vz = piz - pjz;
        const float dij = sqrtf(vx * vx + vy * vy + vz * vz);
        const float rel[10] = {pix, piy, piz, pjx, pjy, pjz, vx, vy, vz, dij};
        const int c0 = half * 16;
#pragma unroll
        for (int c = 0; c < 16; c += 2) {
            float a0 = Pl[320 + c0 + c], a1 = Pl[320 + c0 + c + 1];
#pragma unroll
            for (int i = 0; i < 10; ++i) {
                a0 += rel[i] * Pl[i * 32 + c0 + c];
                a1 += rel[i] * Pl[i * 32 + c0 + c + 1];
            }
            ((unsigned*)Fl)[(e * 72 + 32 + c0 + c) >> 1] = pack2(fmaxf(a0, 0.f), fmaxf(a1, 0.f));
        }
    }
    __syncthreads();

    const int lane = t & 63, w = t >> 6, quad = lane >> 4, c16 = lane & 15;
    f32x4 acc[2][4];
#pragma unroll
    for (int mt = 0; mt < 2; ++mt)
#pragma unroll
        for (int nt = 0; nt < 4; ++nt)
#pragma unroll
            for (int r = 0; r < 4; ++r) acc[mt][nt][r] = 0.f;
#pragma unroll
    for (int ks = 0; ks < 2; ++ks) {
        bf16x8 a[2], b[4];
#pragma unroll
        for (int mt = 0; mt < 2; ++mt)
            a[mt] = *(const bf16x8*)&Fl[(w * 32 + mt * 16 + c16) * 72 + ks * 32 + quad * 8];
#pragma unroll
        for (int nt = 0; nt < 4; ++nt)
            b[nt] = *(const bf16x8*)&Wl[(nt * 16 + c16) * 72 + ks * 32 + quad * 8];
#pragma unroll
        for (int mt = 0; mt < 2; ++mt)
#pragma unroll
            for (int nt = 0; nt < 4; ++nt) MFMA16(acc[mt][nt], a[mt], b[nt]);
    }
    float bcol[4];
#pragma unroll
    for (int nt = 0; nt < 4; ++nt) bcol[nt] = batt[nt * 16 + c16];

#pragma unroll
    for (int mt = 0; mt < 2; ++mt) {
#pragma unroll
        for (int nt = 0; nt < 4; ++nt)
#pragma unroll
            for (int r = 0; r < 4; ++r)
                acc[mt][nt][r] = fmaxf(acc[mt][nt][r] + bcol[nt], 0.f);
        float rs[4];
#pragma unroll
        for (int r = 0; r < 4; ++r) {
            float mx = acc[mt][0][r];
#pragma unroll
            for (int nt = 1; nt < 4; ++nt) mx = fmaxf(mx, acc[mt][nt][r]);
            mx = fmaxf(mx, __shfl_xor(mx, 1));
            mx = fmaxf(mx, __shfl_xor(mx, 2));
            mx = fmaxf(mx, __shfl_xor(mx, 4));
            mx = fmaxf(mx, __shfl_xor(mx, 8));
            float sm = 0.f;
#pragma unroll
            for (int nt = 0; nt < 4; ++nt) {
                acc[mt][nt][r] = __expf(acc[mt][nt][r] - mx);
                sm += acc[mt][nt][r];
            }
            sm += __shfl_xor(sm, 1);
            sm += __shfl_xor(sm, 2);
            sm += __shfl_xor(sm, 4);
            sm += __shfl_xor(sm, 8);
            rs[r] = 1.f / sm;
        }
#pragma unroll
        for (int nt = 0; nt < 4; ++nt) {
            float v = 0.f;
#pragma unroll
            for (int r = 0; r < 4; ++r) {
                const float fv = bfu2f(Fl[(w * 32 + mt * 16 + quad * 4 + r) * 72 + nt * 16 + c16]);
                v += acc[mt][nt][r] * rs[r] * fv;
            }
            v += __shfl_xor(v, 16);
            v += __shfl_xor(v, 32);
            if (lane < 16)
                agg1w[(size_t)(d0 + w * 2 + mt) * 64 + nt * 16 + c16] = f2bf(v);
        }
    }
}

// ---------------------------------------------------------------------------
// k_gemm1: h1 = relu(agg1 @ Wg1 + bg1), 128 rows/block, bf16 out
// ---------------------------------------------------------------------------
__global__ __launch_bounds__(256) void k_gemm1(
    const ushortT* __restrict__ agg1w, const ushortT* __restrict__ wsw,
    const float* __restrict__ bg, ushortT* __restrict__ h1w)
{
    __shared__ ushortT Al[128 * 72];
    __shared__ ushortT Wl[64 * 72];
    const int t = threadIdx.x;
    const int d0 = blockIdx.x * 128;

    for (int i = t; i < 4096; i += 256) {
        const int r = i >> 5, j = i & 31;
        ((unsigned*)Al)[r * 36 + j] = ((const unsigned*)agg1w)[(size_t)(d0 + r) * 32 + j];
    }
    {
        const unsigned* wsrc = (const unsigned*)(wsw + WS_WGT1);
        for (int i = t; i < 2304; i += 256) ((unsigned*)Wl)[i] = wsrc[i];
    }
    __syncthreads();

    const int lane = t & 63, w = t >> 6, quad = lane >> 4, c16 = lane & 15;
    f32x4 acc[2][4];
#pragma unroll
    for (int mt = 0; mt < 2; ++mt)
#pragma unroll
        for (int nt = 0; nt < 4; ++nt)
#pragma unroll
            for (int r = 0; r < 4; ++r) acc[mt][nt][r] = 0.f;
#pragma unroll
    for (int ks = 0; ks < 2; ++ks) {
        bf16x8 a[2], b[4];
#pragma unroll
        for (int mt = 0; mt < 2; ++mt)
            a[mt] = *(const bf16x8*)&Al[(w * 32 + mt * 16 + c16) * 72 + ks * 32 + quad * 8];
#pragma unroll
        for (int nt = 0; nt < 4; ++nt)
            b[nt] = *(const bf16x8*)&Wl[(nt * 16 + c16) * 72 + ks * 32 + quad * 8];
#pragma unroll
        for (int mt = 0; mt < 2; ++mt)
#pragma unroll
            for (int nt = 0; nt < 4; ++nt) MFMA16(acc[mt][nt], a[mt], b[nt]);
    }
#pragma unroll
    for (int nt = 0; nt < 4; ++nt) {
        const int col = nt * 16 + c16;
        const float bias = bg[col];
#pragma unroll
        for (int mt = 0; mt < 2; ++mt)
#pragma unroll
            for (int r = 0; r < 4; ++r) {
                const int row = d0 + w * 32 + mt * 16 + quad * 4 + r;
                h1w[(size_t)row * 64 + col] = f2bf(fmaxf(acc[mt][nt][r] + bias, 0.f));
            }
    }
}

// ---------------------------------------------------------------------------
// k_conv2: 8 nodes/block, F=[128 edges][128 ch] bf16, MFMA attention -> agg2
// ---------------------------------------------------------------------------
__global__ __launch_bounds__(256) void k_conv2(
    const ushortT* __restrict__ h1w, const float* __restrict__ pos,
    const int* __restrict__ idx1, const int* __restrict__ idx2,
    const int* __restrict__ src2,
    const float* __restrict__ Wpp, const float* __restrict__ bpp,
    const ushortT* __restrict__ wsw, const float* __restrict__ batt,
    ushortT* __restrict__ agg2w)
{
    __shared__ ushortT Fl[128 * 136];
    __shared__ ushortT Wl[128 * 136];
    __shared__ float Pl[704];          // Wpp2 [10][64] + bpp2[64]
    const int t = threadIdx.x;
    const int d0 = blockIdx.x * 8;

    {
        const unsigned* wsrc = (const unsigned*)(wsw + WS_WAT2);
        for (int i = t; i < 8704; i += 256) ((unsigned*)Wl)[i] = wsrc[i];
        for (int i = t; i < 704; i += 256) Pl[i] = (i < 640) ? Wpp[i] : bpp[i - 640];
    }
    __syncthreads();

    {   // build F: 2 threads/edge
        const int e = t >> 1, half = t & 1;
        const int g = e >> 4;
        const int s = src2[(d0 + g) * 16 + (e & 15)];
        const unsigned* srcp = (const unsigned*)h1w + (size_t)s * 32 + half * 16;
        unsigned* dstp = (unsigned*)Fl + e * 68 + half * 16;
#pragma unroll
        for (int j = 0; j < 16; ++j) dstp[j] = srcp[j];

        const int pin = idx1[idx2[d0 + g]];
        const int sn = idx1[s];
        const float pix = pos[pin * 3 + 0], piy = pos[pin * 3 + 1], piz = pos[pin * 3 + 2];
        const float pjx = pos[sn * 3 + 0],  pjy = pos[sn * 3 + 1],  pjz = pos[sn * 3 + 2];
        const float vx = pix - pjx, vy = piy - pjy, vz = piz - pjz;
        const float dij = sqrtf(vx * vx + vy * vy + vz * vz);
        const float rel[10] = {pix, piy, piz, pjx, pjy, pjz, vx, vy, vz, dij};
        const int c0 = half * 32;
#pragma unroll
        for (int c = 0; c < 32; c += 2) {
            float a0 = Pl[640 + c0 + c], a1 = Pl[640 + c0 + c + 1];
#pragma unroll
            for (int i = 0; i < 10; ++i) {
                a0 += rel[i] * Pl[i * 64 + c0 + c];
                a1 += rel[i] * Pl[i * 64 + c0 + c + 1];
            }
            ((unsigned*)Fl)[(e * 136 + 64 + c0 + c) >> 1] = pack2(fmaxf(a0, 0.f), fmaxf(a1, 0.f));
        }
    }
    __syncthreads();

    const int lane = t & 63, w = t >> 6, quad = lane >> 4, c16 = lane & 15;
    f32x4 acc[2][8];
#pragma unroll
    for (int mt = 0; mt < 2; ++mt)
#pragma unroll
        for (int nt = 0; nt < 8; ++nt)
#pragma unroll
            for (int r = 0; r < 4; ++r) acc[mt][nt][r] = 0.f;
#pragma unroll
    for (int ks = 0; ks < 4; ++ks) {
        bf16x8 a[2], b[8];
#pragma unroll
        for (int mt = 0; mt < 2; ++mt)
            a[mt] = *(const bf16x8*)&Fl[(w * 32 + mt * 16 + c16) * 136 + ks * 32 + quad * 8];
#pragma unroll
        for (int nt = 0; nt < 8; ++nt)
            b[nt] = *(const bf16x8*)&Wl[(nt * 16 + c16) * 136 + ks * 32 + quad * 8];
#pragma unroll
        for (int mt = 0; mt < 2; ++mt)
#pragma unroll
            for (int nt = 0; nt < 8; ++nt) MFMA16(acc[mt][nt], a[mt], b[nt]);
    }
    float bcol[8];
#pragma unroll
    for (int nt = 0; nt < 8; ++nt) bcol[nt] = batt[nt * 16 + c16];

#pragma unroll
    for (int mt = 0; mt < 2; ++mt) {
#pragma unroll
        for (int nt = 0; nt < 8; ++nt)
#pragma unroll
            for (int r = 0; r < 4; ++r)
                acc[mt][nt][r] = fmaxf(acc[mt][nt][r] + bcol[nt], 0.f);
        float rs[4];
#pragma unroll
        for (int r = 0; r < 4; ++r) {
            float mx = acc[mt][0][r];
#pragma unroll
            for (int nt = 1; nt < 8; ++nt) mx = fmaxf(mx, acc[mt][nt][r]);
            mx = fmaxf(mx, __shfl_xor(mx, 1));
            mx = fmaxf(mx, __shfl_xor(mx, 2));
            mx = fmaxf(mx, __shfl_xor(mx, 4));
            mx = fmaxf(mx, __shfl_xor(mx, 8));
            float sm = 0.f;
#pragma unroll
            for (int nt = 0; nt < 8; ++nt) {
                acc[mt][nt][r] = __expf(acc[mt][nt][r] - mx);
                sm += acc[mt][nt][r];
            }
            sm += __shfl_xor(sm, 1);
            sm += __shfl_xor(sm, 2);
            sm += __shfl_xor(sm, 4);
            sm += __shfl_xor(sm, 8);
            rs[r] = 1.f / sm;
        }
#pragma unroll
        for (int nt = 0; nt < 8; ++nt) {
            float v = 0.f;
#pragma unroll
            for (int r = 0; r < 4; ++r) {
                const float fv = bfu2f(Fl[(w * 32 + mt * 16 + quad * 4 + r) * 136 + nt * 16 + c16]);
                v += acc[mt][nt][r] * rs[r] * fv;
            }
            v += __shfl_xor(v, 16);
            v += __shfl_xor(v, 32);
            if (lane < 16)
                agg2w[(size_t)(d0 + w * 2 + mt) * 128 + nt * 16 + c16] = f2bf(v);
        }
    }
}

// ---------------------------------------------------------------------------
// k_post: h2=relu(agg2@Wg2+bg2); u=relu(h2@Wup+bup); sc=relu(x2@Wsc+bsc);
// out=u+sc. 64 nodes/block, three chained MFMA GEMMs.
// ---------------------------------------------------------------------------
__global__ __launch_bounds__(256) void k_post(
    const ushortT* __restrict__ agg2w, const float* __restrict__ x,
    const int* __restrict__ idx1, const int* __restrict__ idx2,
    const ushortT* __restrict__ wsw,
    const float* __restrict__ bg, const float* __restrict__ bup,
    const float* __restrict__ bsc, float* __restrict__ out)
{
    __shared__ ushortT Al[64 * 136];
    __shared__ ushortT Wl[128 * 136];
    __shared__ ushortT Bl[64 * 136];
    __shared__ ushortT A2[64 * 72];
    const int t = threadIdx.x;
    const int d0 = blockIdx.x * 64;

    // stage agg2 rows
    for (int i = t; i < 4096; i += 256) {
        const int r = i >> 6, j = i & 63;
        ((unsigned*)Al)[r * 68 + j] = ((const unsigned*)agg2w)[(size_t)(d0 + r) * 64 + j];
    }
    // stage shortcut x rows (gather + cvt)
    {
        const int r = t >> 2, q = t & 3;
        const int pin = idx1[idx2[d0 + r]];
        const float* src = &x[(size_t)pin * 64 + q * 16];
        unsigned* dst = (unsigned*)A2 + r * 36 + q * 8;
#pragma unroll
        for (int j = 0; j < 8; ++j) {
            const float2 v = *reinterpret_cast<const float2*>(src + j * 2);
            dst[j] = pack2(v.x, v.y);
        }
    }
    {
        const unsigned* wsrc = (const unsigned*)(wsw + WS_WGT2);
        for (int i = t; i < 8704; i += 256) ((unsigned*)Wl)[i] = wsrc[i];
    }
    __syncthreads();

    const int lane = t & 63, w = t >> 6, quad = lane >> 4, c16 = lane & 15;

    // ---- GEMM1: h2 = relu(agg2 @ Wg2 + bg2) -> Bl (bf16, A-layout) ----
    {
        f32x4 acc[8];
#pragma unroll
        for (int nt = 0; nt < 8; ++nt)
#pragma unroll
            for (int r = 0; r < 4; ++r) acc[nt][r] = 0.f;
#pragma unroll
        for (int ks = 0; ks < 4; ++ks) {
            const bf16x8 a = *(const bf16x8*)&Al[(w * 16 + c16) * 136 + ks * 32 + quad * 8];
#pragma unroll
            for (int nt = 0; nt < 8; ++nt) {
                const bf16x8 b = *(const bf16x8*)&Wl[(nt * 16 + c16) * 136 + ks * 32 + quad * 8];
                MFMA16(acc[nt], a, b);
            }
        }
#pragma unroll
        for (int nt = 0; nt < 8; ++nt) {
            const int col = nt * 16 + c16;
            const float bias = bg[col];
#pragma unroll
            for (int r = 0; r < 4; ++r)
                Bl[(w * 16 + quad * 4 + r) * 136 + col] = f2bf(fmaxf(acc[nt][r] + bias, 0.f));
        }
    }
    __syncthreads();
    {   // restage Wl <- WupT
        const unsigned* wsrc = (const unsigned*)(wsw + WS_WUPT);
        for (int i = t; i < 8704; i += 256) ((unsigned*)Wl)[i] = wsrc[i];
    }
    __syncthreads();

    // ---- GEMM2: u = relu(h2 @ Wup + bup), keep in regs ----
    f32x4 u[8];
    {
#pragma unroll
        for (int nt = 0; nt < 8; ++nt)
#pragma unroll
            for (int r = 0; r < 4; ++r) u[nt][r] = 0.f;
#pragma unroll
        for (int ks = 0; ks < 4; ++ks) {
            const bf16x8 a = *(const bf16x8*)&Bl[(w * 16 + c16) * 136 + ks * 32 + quad * 8];
#pragma unroll
            for (int nt = 0; nt < 8; ++nt) {
                const bf16x8 b = *(const bf16x8*)&Wl[(nt * 16 + c16) * 136 + ks * 32 + quad * 8];
                MFMA16(u[nt], a, b);
            }
        }
#pragma unroll
        for (int nt = 0; nt < 8; ++nt) {
            const float bias = bup[nt * 16 + c16];
#pragma unroll
            for (int r = 0; r < 4; ++r) u[nt][r] = fmaxf(u[nt][r] + bias, 0.f);
        }
    }
    __syncthreads();
    {   // restage Wl <- WscT (stride 72)
        const unsigned* wsrc = (const unsigned*)(wsw + WS_WSCT);
        for (int i = t; i < 4608; i += 256) ((unsigned*)Wl)[i] = wsrc[i];
    }
    __syncthreads();

    // ---- GEMM3: sc = relu(x2 @ Wsc + bsc); out = u + sc ----
    {
        f32x4 acc[8];
#pragma unroll
        for (int nt = 0; nt < 8; ++nt)
#pragma unroll
            for (int r = 0; r < 4; ++r) acc[nt][r] = 0.f;
        const ushortT* Wsc_l = Wl;   // [128][72]
#pragma unroll
        for (int ks = 0; ks < 2; ++ks) {
            const bf16x8 a = *(const bf16x8*)&A2[(w * 16 + c16) * 72 + ks * 32 + quad * 8];
#pragma unroll
            for (int nt = 0; nt < 8; ++nt) {
                const bf16x8 b = *(const bf16x8*)&Wsc_l[(nt * 16 + c16) * 72 + ks * 32 + quad * 8];
                MFMA16(acc[nt], a, b);
            }
        }
#pragma unroll
        for (int nt = 0; nt < 8; ++nt) {
            const int col = nt * 16 + c16;
            const float bias = bsc[col];
#pragma unroll
            for (int r = 0; r < 4; ++r) {
                const float sc = fmaxf(acc[nt][r] + bias, 0.f);
                const int row = d0 + w * 16 + quad * 4 + r;
                out[(size_t)row * 128 + col] = u[nt][r] + sc;   // both >=0, final relu no-op
            }
        }
    }
}

extern "C" void kernel_launch(void* const* d_in, const int* in_sizes, int n_in,
                              void* d_out, int out_size, void* d_ws, size_t ws_size,
                              hipStream_t stream)
{
    const float* x      = (const float*)d_in[0];
    const float* pos    = (const float*)d_in[1];
    const float* W_down = (const float*)d_in[2];
    const float* b_down = (const float*)d_in[3];
    const float* W_pp1  = (const float*)d_in[4];
    const float* b_pp1  = (const float*)d_in[5];
    const float* W_att1 = (const float*)d_in[6];
    const float* b_att1 = (const float*)d_in[7];
    const float* W_g1   = (const float*)d_in[8];
    const float* b_g1   = (const float*)d_in[9];
    const float* W_pp2  = (const float*)d_in[10];
    const float* b_pp2  = (const float*)d_in[11];
    const float* W_att2 = (const float*)d_in[12];
    const float* b_att2 = (const float*)d_in[13];
    const float* W_g2   = (const float*)d_in[14];
    const float* b_g2   = (const float*)d_in[15];
    const float* W_up   = (const float*)d_in[16];
    const float* b_up   = (const float*)d_in[17];
    const float* W_sc   = (const float*)d_in[18];
    const float* b_sc   = (const float*)d_in[19];
    const int* idx1 = (const int*)d_in[20];
    const int* idx2 = (const int*)d_in[21];
    const int* src1 = (const int*)d_in[22];
    const int* src2 = (const int*)d_in[24];

    ushortT* wsw = (ushortT*)d_ws;
    ushortT* h0w   = wsw + WS_H0;
    ushortT* h1w   = wsw + WS_H1;
    ushortT* agg1w = wsw + WS_AGG1;
    ushortT* agg2w = wsw + WS_AGG2;

    k_prep <<<68, 256, 0, stream>>>(W_down, W_att1, W_g1, W_att2, W_g2, W_up, W_sc, wsw);
    k_down <<<N_FULL / 128, 256, 0, stream>>>(x, wsw, b_down, h0w);
    k_conv1<<<NN1 / 8, 256, 0, stream>>>(h0w, pos, idx1, src1,
                                         W_pp1, b_pp1, wsw, b_att1, agg1w);
    k_gemm1<<<NN1 / 128, 256, 0, stream>>>(agg1w, wsw, b_g1, h1w);
    k_conv2<<<NN2 / 8, 256, 0, stream>>>(h1w, pos, idx1, idx2, src2,
                                         W_pp2, b_pp2, wsw, b_att2, agg2w);
    k_post <<<NN2 / 64, 256, 0, stream>>>(agg2w, x, idx1, idx2, wsw,
                                          b_g2, b_up, b_sc, (float*)d_out);
}

// Round 6
// 183.401 us; speedup vs baseline: 3.3778x; 1.1068x over previous
//
#include <hip/hip_runtime.h>

#define N_FULL 65536
#define NN1    16384
#define NN2    8192

typedef __attribute__((ext_vector_type(8))) short bf16x8;
typedef __attribute__((ext_vector_type(4))) float f32x4;
typedef unsigned short ushortT;

#define MFMA16(acc, a, b) acc = __builtin_amdgcn_mfma_f32_16x16x32_bf16(a, b, acc, 0, 0, 0)

static __device__ __forceinline__ ushortT f2bf(float f) {
    union { float f; unsigned u; } v; v.f = f;
    unsigned r = v.u + 0x7FFFu + ((v.u >> 16) & 1u);
    return (ushortT)(r >> 16);
}
static __device__ __forceinline__ unsigned pack2(float a, float b) {
    return (unsigned)f2bf(a) | ((unsigned)f2bf(b) << 16);
}
static __device__ __forceinline__ float bfu2f(ushortT h) {
    union { unsigned u; float f; } v; v.u = (unsigned)h << 16; return v.f;
}

// ws layout (ushort units) — all byte offsets 16B-aligned
#define WS_WDT   0        /* [32][72]   */
#define WS_WAT1  2304     /* [64][72]   */
#define WS_WGT1  6912     /* [64][72]   */
#define WS_WAT2  11520    /* [128][136] */
#define WS_WGT2  28928    /* [128][136] */
#define WS_WUPT  46336    /* [128][136] */
#define WS_WSCT  63744    /* [128][72]  */
#define WS_H0    73728    /* bf16 [65536][32] */
#define WS_H1    (WS_H0 + 65536u*32u)
#define WS_AGG2  (WS_H1 + 16384u*64u)

// ---------------------------------------------------------------------------
// k_prep: transpose weights to [n][k] bf16 with padded row stride
// ---------------------------------------------------------------------------
static __device__ __forceinline__ void tpose(
    const float* __restrict__ src, ushortT* __restrict__ dst,
    int K, int N, int STR, int gid, int gs)
{
    for (int i = gid; i < K * N; i += gs) {
        const int n = i / K, k = i - n * K;
        dst[n * STR + k] = f2bf(src[(size_t)k * N + n]);
    }
}

__global__ __launch_bounds__(256) void k_prep(
    const float* __restrict__ Wd, const float* __restrict__ Wa1,
    const float* __restrict__ Wg1, const float* __restrict__ Wa2,
    const float* __restrict__ Wg2, const float* __restrict__ Wup,
    const float* __restrict__ Wsc, ushortT* __restrict__ wsw)
{
    const int gid = blockIdx.x * 256 + threadIdx.x, gs = gridDim.x * 256;
    tpose(Wd,  wsw + WS_WDT,  64, 32, 72,  gid, gs);
    tpose(Wa1, wsw + WS_WAT1, 64, 64, 72,  gid, gs);
    tpose(Wg1, wsw + WS_WGT1, 64, 64, 72,  gid, gs);
    tpose(Wa2, wsw + WS_WAT2, 128, 128, 136, gid, gs);
    tpose(Wg2, wsw + WS_WGT2, 128, 128, 136, gid, gs);
    tpose(Wup, wsw + WS_WUPT, 128, 128, 136, gid, gs);
    tpose(Wsc, wsw + WS_WSCT, 64, 128, 72, gid, gs);
}

// ---------------------------------------------------------------------------
// k_down: h0 = relu(x @ Wd + bd) bf16, MFMA. 128 rows/block.
// ---------------------------------------------------------------------------
__global__ __launch_bounds__(256) void k_down(
    const float* __restrict__ x, const ushortT* __restrict__ wsw,
    const float* __restrict__ bd, ushortT* __restrict__ h0w)
{
    __shared__ __align__(16) ushortT Al[128 * 72];
    __shared__ __align__(16) ushortT Bl[32 * 72];
    const int t = threadIdx.x;
    const int rowBase = blockIdx.x * 128;

    {   // stage A: x rows -> bf16 LDS
        const int r = t >> 1, c0 = (t & 1) * 32;
        unsigned* dst = (unsigned*)Al + r * 36 + (c0 >> 1);
        const float* src = &x[(size_t)(rowBase + r) * 64 + c0];
#pragma unroll
        for (int j = 0; j < 32; j += 4) {
            const float4 v = *reinterpret_cast<const float4*>(src + j);
            dst[(j >> 1) + 0] = pack2(v.x, v.y);
            dst[(j >> 1) + 1] = pack2(v.z, v.w);
        }
        const uint4* wsrc = (const uint4*)(wsw + WS_WDT);
        uint4* bl4 = (uint4*)Bl;
        for (int i = t; i < 288; i += 256) bl4[i] = wsrc[i];
    }
    __syncthreads();

    const int lane = t & 63, w = t >> 6, quad = lane >> 4, c16 = lane & 15;
    f32x4 acc[2][2];
#pragma unroll
    for (int mt = 0; mt < 2; ++mt)
#pragma unroll
        for (int nt = 0; nt < 2; ++nt)
#pragma unroll
            for (int r = 0; r < 4; ++r) acc[mt][nt][r] = 0.f;
#pragma unroll
    for (int ks = 0; ks < 2; ++ks) {
        bf16x8 a[2], b[2];
#pragma unroll
        for (int mt = 0; mt < 2; ++mt)
            a[mt] = *(const bf16x8*)&Al[(w * 32 + mt * 16 + c16) * 72 + ks * 32 + quad * 8];
#pragma unroll
        for (int nt = 0; nt < 2; ++nt)
            b[nt] = *(const bf16x8*)&Bl[(nt * 16 + c16) * 72 + ks * 32 + quad * 8];
#pragma unroll
        for (int mt = 0; mt < 2; ++mt)
#pragma unroll
            for (int nt = 0; nt < 2; ++nt) MFMA16(acc[mt][nt], a[mt], b[nt]);
    }
#pragma unroll
    for (int nt = 0; nt < 2; ++nt) {
        const int col = nt * 16 + c16;
        const float bias = bd[col];
#pragma unroll
        for (int mt = 0; mt < 2; ++mt)
#pragma unroll
            for (int r = 0; r < 4; ++r) {
                const int row = rowBase + w * 32 + mt * 16 + quad * 4 + r;
                h0w[(size_t)row * 32 + col] = f2bf(fmaxf(acc[mt][nt][r] + bias, 0.f));
            }
    }
}

// ---------------------------------------------------------------------------
// k_conv1: 8 nodes/block; F=[128 edges][64 ch] bf16; MFMA attention +
// in-wave softmax + aggregate -> LDS; fused global_nn GEMM -> h1 directly.
// ---------------------------------------------------------------------------
__global__ __launch_bounds__(256) void k_conv1(
    const ushortT* __restrict__ h0w, const float* __restrict__ pos,
    const int* __restrict__ idx1, const int* __restrict__ src1,
    const float* __restrict__ Wpp, const float* __restrict__ bpp,
    const ushortT* __restrict__ wsw, const float* __restrict__ batt,
    const float* __restrict__ bg, ushortT* __restrict__ h1w)
{
    __shared__ __align__(16) ushortT Fl[128 * 72];    // 18 KB
    __shared__ __align__(16) ushortT Wl[64 * 72];     // 9 KB  Watt1^T
    __shared__ __align__(16) ushortT Gl[64 * 72];     // 9 KB  Wg1^T
    __shared__ __align__(16) ushortT A2ls[16 * 72];   // agg rows (8 used)
    __shared__ float Pl[352];                         // Wpp1 [10][32] + bpp1[32]
    const int t = threadIdx.x;
    const int d0 = blockIdx.x * 8;

    {   // stage weights (uint4) + zero agg padding rows 8..15
        const uint4* wa = (const uint4*)(wsw + WS_WAT1);
        const uint4* wg = (const uint4*)(wsw + WS_WGT1);
        uint4* wl4 = (uint4*)Wl;
        uint4* gl4 = (uint4*)Gl;
        for (int i = t; i < 576; i += 256) { wl4[i] = wa[i]; gl4[i] = wg[i]; }
        for (int i = t; i < 352; i += 256) Pl[i] = (i < 320) ? Wpp[i] : bpp[i - 320];
        for (int i = t; i < 288; i += 256) ((unsigned*)A2ls)[288 + i] = 0;
    }

    {   // build F: 2 threads/edge
        const int e = t >> 1, half = t & 1;
        const int g = e >> 4;
        const int s = src1[(d0 + g) * 16 + (e & 15)];
        const uint4* srcp = (const uint4*)((const unsigned*)h0w + (size_t)s * 16 + half * 8);
        uint4* dstp = (uint4*)((unsigned*)Fl + e * 36 + half * 8);
        dstp[0] = srcp[0];
        dstp[1] = srcp[1];

        const int pin = idx1[d0 + g];
        const float pix = pos[pin * 3 + 0], piy = pos[pin * 3 + 1], piz = pos[pin * 3 + 2];
        const float pjx = pos[s * 3 + 0],  pjy = pos[s * 3 + 1],  pjz = pos[s * 3 + 2];
        const float vx = pix - pjx, vy = piy - pjy, vz = piz - pjz;
        const float dij = sqrtf(vx * vx + vy * vy + vz * vz);
        const float rel[10] = {pix, piy, piz, pjx, pjy, pjz, vx, vy, vz, dij};
        __syncthreads();    // Pl ready (staged above), also covers Wl/Gl
        const int c0 = half * 16;
#pragma unroll
        for (int c = 0; c < 16; c += 2) {
            float a0 = Pl[320 + c0 + c], a1 = Pl[320 + c0 + c + 1];
#pragma unroll
            for (int i = 0; i < 10; ++i) {
                a0 += rel[i] * Pl[i * 32 + c0 + c];
                a1 += rel[i] * Pl[i * 32 + c0 + c + 1];
            }
            ((unsigned*)Fl)[(e * 72 + 32 + c0 + c) >> 1] = pack2(fmaxf(a0, 0.f), fmaxf(a1, 0.f));
        }
    }
    __syncthreads();

    const int lane = t & 63, w = t >> 6, quad = lane >> 4, c16 = lane & 15;
    f32x4 acc[2][4];
#pragma unroll
    for (int mt = 0; mt < 2; ++mt)
#pragma unroll
        for (int nt = 0; nt < 4; ++nt)
#pragma unroll
            for (int r = 0; r < 4; ++r) acc[mt][nt][r] = 0.f;
#pragma unroll
    for (int ks = 0; ks < 2; ++ks) {
        bf16x8 a[2], b[4];
#pragma unroll
        for (int mt = 0; mt < 2; ++mt)
            a[mt] = *(const bf16x8*)&Fl[(w * 32 + mt * 16 + c16) * 72 + ks * 32 + quad * 8];
#pragma unroll
        for (int nt = 0; nt < 4; ++nt)
            b[nt] = *(const bf16x8*)&Wl[(nt * 16 + c16) * 72 + ks * 32 + quad * 8];
#pragma unroll
        for (int mt = 0; mt < 2; ++mt)
#pragma unroll
            for (int nt = 0; nt < 4; ++nt) MFMA16(acc[mt][nt], a[mt], b[nt]);
    }
    float bcol[4];
#pragma unroll
    for (int nt = 0; nt < 4; ++nt) bcol[nt] = batt[nt * 16 + c16];

#pragma unroll
    for (int mt = 0; mt < 2; ++mt) {
#pragma unroll
        for (int nt = 0; nt < 4; ++nt)
#pragma unroll
            for (int r = 0; r < 4; ++r)
                acc[mt][nt][r] = fmaxf(acc[mt][nt][r] + bcol[nt], 0.f);
        float rs[4];
#pragma unroll
        for (int r = 0; r < 4; ++r) {
            float mx = acc[mt][0][r];
#pragma unroll
            for (int nt = 1; nt < 4; ++nt) mx = fmaxf(mx, acc[mt][nt][r]);
            mx = fmaxf(mx, __shfl_xor(mx, 1));
            mx = fmaxf(mx, __shfl_xor(mx, 2));
            mx = fmaxf(mx, __shfl_xor(mx, 4));
            mx = fmaxf(mx, __shfl_xor(mx, 8));
            float sm = 0.f;
#pragma unroll
            for (int nt = 0; nt < 4; ++nt) {
                acc[mt][nt][r] = __expf(acc[mt][nt][r] - mx);
                sm += acc[mt][nt][r];
            }
            sm += __shfl_xor(sm, 1);
            sm += __shfl_xor(sm, 2);
            sm += __shfl_xor(sm, 4);
            sm += __shfl_xor(sm, 8);
            rs[r] = 1.f / sm;
        }
#pragma unroll
        for (int nt = 0; nt < 4; ++nt) {
            float v = 0.f;
#pragma unroll
            for (int r = 0; r < 4; ++r) {
                const float fv = bfu2f(Fl[(w * 32 + mt * 16 + quad * 4 + r) * 72 + nt * 16 + c16]);
                v += acc[mt][nt][r] * rs[r] * fv;
            }
            v += __shfl_xor(v, 16);
            v += __shfl_xor(v, 32);
            if (lane < 16)
                A2ls[(w * 2 + mt) * 72 + nt * 16 + c16] = f2bf(v);
        }
    }
    __syncthreads();

    // ---- fused global_nn: h1 = relu(agg @ Wg1 + bg1); wave w = N-tile w ----
    {
        f32x4 acc2 = {0.f, 0.f, 0.f, 0.f};
#pragma unroll
        for (int ks = 0; ks < 2; ++ks) {
            const bf16x8 a = *(const bf16x8*)&A2ls[c16 * 72 + ks * 32 + quad * 8];
            const bf16x8 b = *(const bf16x8*)&Gl[(w * 16 + c16) * 72 + ks * 32 + quad * 8];
            MFMA16(acc2, a, b);
        }
        const int col = w * 16 + c16;
        const float bias = bg[col];
        if (quad < 2) {     // rows 0..7 valid
#pragma unroll
            for (int r = 0; r < 4; ++r) {
                const int row = quad * 4 + r;
                h1w[(size_t)(d0 + row) * 64 + col] = f2bf(fmaxf(acc2[r] + bias, 0.f));
            }
        }
    }
}

// ---------------------------------------------------------------------------
// k_conv2: 8 nodes/block, F=[128 edges][128 ch] bf16, MFMA attention -> agg2
// ---------------------------------------------------------------------------
__global__ __launch_bounds__(256) void k_conv2(
    const ushortT* __restrict__ h1w, const float* __restrict__ pos,
    const int* __restrict__ idx1, const int* __restrict__ idx2,
    const int* __restrict__ src2,
    const float* __restrict__ Wpp, const float* __restrict__ bpp,
    const ushortT* __restrict__ wsw, const float* __restrict__ batt,
    ushortT* __restrict__ agg2w)
{
    __shared__ __align__(16) ushortT Fl[128 * 136];
    __shared__ __align__(16) ushortT Wl[128 * 136];
    __shared__ float Pl[704];          // Wpp2 [10][64] + bpp2[64]
    const int t = threadIdx.x;
    const int d0 = blockIdx.x * 8;

    {
        const uint4* wsrc = (const uint4*)(wsw + WS_WAT2);
        uint4* wl4 = (uint4*)Wl;
        for (int i = t; i < 2176; i += 256) wl4[i] = wsrc[i];
        for (int i = t; i < 704; i += 256) Pl[i] = (i < 640) ? Wpp[i] : bpp[i - 640];
    }

    {   // build F: 2 threads/edge
        const int e = t >> 1, half = t & 1;
        const int g = e >> 4;
        const int s = src2[(d0 + g) * 16 + (e & 15)];
        const uint4* srcp = (const uint4*)((const unsigned*)h1w + (size_t)s * 32 + half * 16);
        uint4* dstp = (uint4*)((unsigned*)Fl + e * 68 + half * 16);
#pragma unroll
        for (int j = 0; j < 4; ++j) dstp[j] = srcp[j];

        const int pin = idx1[idx2[d0 + g]];
        const int sn = idx1[s];
        const float pix = pos[pin * 3 + 0], piy = pos[pin * 3 + 1], piz = pos[pin * 3 + 2];
        const float pjx = pos[sn * 3 + 0],  pjy = pos[sn * 3 + 1],  pjz = pos[sn * 3 + 2];
        const float vx = pix - pjx, vy = piy - pjy, vz = piz - pjz;
        const float dij = sqrtf(vx * vx + vy * vy + vz * vz);
        const float rel[10] = {pix, piy, piz, pjx, pjy, pjz, vx, vy, vz, dij};
        __syncthreads();    // Pl ready
        const int c0 = half * 32;
#pragma unroll
        for (int c = 0; c < 32; c += 2) {
            float a0 = Pl[640 + c0 + c], a1 = Pl[640 + c0 + c + 1];
#pragma unroll
            for (int i = 0; i < 10; ++i) {
                a0 += rel[i] * Pl[i * 64 + c0 + c];
                a1 += rel[i] * Pl[i * 64 + c0 + c + 1];
            }
            ((unsigned*)Fl)[(e * 136 + 64 + c0 + c) >> 1] = pack2(fmaxf(a0, 0.f), fmaxf(a1, 0.f));
        }
    }
    __syncthreads();

    const int lane = t & 63, w = t >> 6, quad = lane >> 4, c16 = lane & 15;
    f32x4 acc[2][8];
#pragma unroll
    for (int mt = 0; mt < 2; ++mt)
#pragma unroll
        for (int nt = 0; nt < 8; ++nt)
#pragma unroll
            for (int r = 0; r < 4; ++r) acc[mt][nt][r] = 0.f;
#pragma unroll
    for (int ks = 0; ks < 4; ++ks) {
        bf16x8 a[2], b[8];
#pragma unroll
        for (int mt = 0; mt < 2; ++mt)
            a[mt] = *(const bf16x8*)&Fl[(w * 32 + mt * 16 + c16) * 136 + ks * 32 + quad * 8];
#pragma unroll
        for (int nt = 0; nt < 8; ++nt)
            b[nt] = *(const bf16x8*)&Wl[(nt * 16 + c16) * 136 + ks * 32 + quad * 8];
#pragma unroll
        for (int mt = 0; mt < 2; ++mt)
#pragma unroll
            for (int nt = 0; nt < 8; ++nt) MFMA16(acc[mt][nt], a[mt], b[nt]);
    }
    float bcol[8];
#pragma unroll
    for (int nt = 0; nt < 8; ++nt) bcol[nt] = batt[nt * 16 + c16];

#pragma unroll
    for (int mt = 0; mt < 2; ++mt) {
#pragma unroll
        for (int nt = 0; nt < 8; ++nt)
#pragma unroll
            for (int r = 0; r < 4; ++r)
                acc[mt][nt][r] = fmaxf(acc[mt][nt][r] + bcol[nt], 0.f);
        float rs[4];
#pragma unroll
        for (int r = 0; r < 4; ++r) {
            float mx = acc[mt][0][r];
#pragma unroll
            for (int nt = 1; nt < 8; ++nt) mx = fmaxf(mx, acc[mt][nt][r]);
            mx = fmaxf(mx, __shfl_xor(mx, 1));
            mx = fmaxf(mx, __shfl_xor(mx, 2));
            mx = fmaxf(mx, __shfl_xor(mx, 4));
            mx = fmaxf(mx, __shfl_xor(mx, 8));
            float sm = 0.f;
#pragma unroll
            for (int nt = 0; nt < 8; ++nt) {
                acc[mt][nt][r] = __expf(acc[mt][nt][r] - mx);
                sm += acc[mt][nt][r];
            }
            sm += __shfl_xor(sm, 1);
            sm += __shfl_xor(sm, 2);
            sm += __shfl_xor(sm, 4);
            sm += __shfl_xor(sm, 8);
            rs[r] = 1.f / sm;
        }
#pragma unroll
        for (int nt = 0; nt < 8; ++nt) {
            float v = 0.f;
#pragma unroll
            for (int r = 0; r < 4; ++r) {
                const float fv = bfu2f(Fl[(w * 32 + mt * 16 + quad * 4 + r) * 136 + nt * 16 + c16]);
                v += acc[mt][nt][r] * rs[r] * fv;
            }
            v += __shfl_xor(v, 16);
            v += __shfl_xor(v, 32);
            if (lane < 16)
                agg2w[(size_t)(d0 + w * 2 + mt) * 128 + nt * 16 + c16] = f2bf(v);
        }
    }
}

// ---------------------------------------------------------------------------
// k_post: 32 nodes/block (256 blocks). h2=relu(agg2@Wg2+bg2);
// u=relu(h2@Wup+bup); sc=relu(x2@Wsc+bsc); out=u+sc.
// wave w: M-tile = w>>1 (16 rows), N-half = (w&1)*4 (4 of 8 n-tiles)
// ---------------------------------------------------------------------------
__global__ __launch_bounds__(256) void k_post(
    const ushortT* __restrict__ agg2w, const float* __restrict__ x,
    const int* __restrict__ idx1, const int* __restrict__ idx2,
    const ushortT* __restrict__ wsw,
    const float* __restrict__ bg, const float* __restrict__ bup,
    const float* __restrict__ bsc, float* __restrict__ out)
{
    __shared__ __align__(16) ushortT Al[32 * 136];
    __shared__ __align__(16) ushortT Wl[128 * 136];
    __shared__ __align__(16) ushortT Bl[32 * 136];
    __shared__ __align__(16) ushortT A2[32 * 72];
    const int t = threadIdx.x;
    const int d0 = blockIdx.x * 32;

    // stage agg2 rows (uint4: 16 per row)
    for (int i = t; i < 512; i += 256) {
        const int r = i >> 4, j = i & 15;
        ((uint4*)((unsigned*)Al + r * 68))[j] =
            ((const uint4*)((const unsigned*)agg2w + (size_t)(d0 + r) * 64))[j];
    }
    // stage shortcut x rows (gather + cvt): 8 threads/row, 8 floats each
    {
        const int r = t >> 3, q = t & 7;
        const int pin = idx1[idx2[d0 + r]];
        const float* src = &x[(size_t)pin * 64 + q * 8];
        unsigned* dst = (unsigned*)A2 + r * 36 + q * 4;
#pragma unroll
        for (int j = 0; j < 4; ++j) {
            const float2 v = *reinterpret_cast<const float2*>(src + j * 2);
            dst[j] = pack2(v.x, v.y);
        }
    }
    {   // stage Wg2^T
        const uint4* wsrc = (const uint4*)(wsw + WS_WGT2);
        uint4* wl4 = (uint4*)Wl;
        for (int i = t; i < 2176; i += 256) wl4[i] = wsrc[i];
    }
    __syncthreads();

    const int lane = t & 63, w = t >> 6, quad = lane >> 4, c16 = lane & 15;
    const int mtw = w >> 1;            // 16-row tile base (rows mtw*16..)
    const int ntb = (w & 1) * 4;       // n-tile range ntb..ntb+3

    // ---- GEMM1: h2 = relu(agg2 @ Wg2 + bg2) -> Bl ----
    {
        f32x4 acc[4];
#pragma unroll
        for (int nt = 0; nt < 4; ++nt)
#pragma unroll
            for (int r = 0; r < 4; ++r) acc[nt][r] = 0.f;
#pragma unroll
        for (int ks = 0; ks < 4; ++ks) {
            const bf16x8 a = *(const bf16x8*)&Al[(mtw * 16 + c16) * 136 + ks * 32 + quad * 8];
#pragma unroll
            for (int nt = 0; nt < 4; ++nt) {
                const bf16x8 b = *(const bf16x8*)&Wl[((ntb + nt) * 16 + c16) * 136 + ks * 32 + quad * 8];
                MFMA16(acc[nt], a, b);
            }
        }
#pragma unroll
        for (int nt = 0; nt < 4; ++nt) {
            const int col = (ntb + nt) * 16 + c16;
            const float bias = bg[col];
#pragma unroll
            for (int r = 0; r < 4; ++r)
                Bl[(mtw * 16 + quad * 4 + r) * 136 + col] = f2bf(fmaxf(acc[nt][r] + bias, 0.f));
        }
    }
    __syncthreads();
    {   // restage Wl <- Wup^T
        const uint4* wsrc = (const uint4*)(wsw + WS_WUPT);
        uint4* wl4 = (uint4*)Wl;
        for (int i = t; i < 2176; i += 256) wl4[i] = wsrc[i];
    }
    __syncthreads();

    // ---- GEMM2: u = relu(h2 @ Wup + bup), keep in regs ----
    f32x4 u[4];
    {
#pragma unroll
        for (int nt = 0; nt < 4; ++nt)
#pragma unroll
            for (int r = 0; r < 4; ++r) u[nt][r] = 0.f;
#pragma unroll
        for (int ks = 0; ks < 4; ++ks) {
            const bf16x8 a = *(const bf16x8*)&Bl[(mtw * 16 + c16) * 136 + ks * 32 + quad * 8];
#pragma unroll
            for (int nt = 0; nt < 4; ++nt) {
                const bf16x8 b = *(const bf16x8*)&Wl[((ntb + nt) * 16 + c16) * 136 + ks * 32 + quad * 8];
                MFMA16(u[nt], a, b);
            }
        }
#pragma unroll
        for (int nt = 0; nt < 4; ++nt) {
            const float bias = bup[(ntb + nt) * 16 + c16];
#pragma unroll
            for (int r = 0; r < 4; ++r) u[nt][r] = fmaxf(u[nt][r] + bias, 0.f);
        }
    }
    __syncthreads();
    {   // restage Wl <- Wsc^T [128][72]
        const uint4* wsrc = (const uint4*)(wsw + WS_WSCT);
        uint4* wl4 = (uint4*)Wl;
        for (int i = t; i < 1152; i += 256) wl4[i] = wsrc[i];
    }
    __syncthreads();

    // ---- GEMM3: sc = relu(x2 @ Wsc + bsc); out = u + sc ----
    {
        f32x4 acc[4];
#pragma unroll
        for (int nt = 0; nt < 4; ++nt)
#pragma unroll
            for (int r = 0; r < 4; ++r) acc[nt][r] = 0.f;
#pragma unroll
        for (int ks = 0; ks < 2; ++ks) {
            const bf16x8 a = *(const bf16x8*)&A2[(mtw * 16 + c16) * 72 + ks * 32 + quad * 8];
#pragma unroll
            for (int nt = 0; nt < 4; ++nt) {
                const bf16x8 b = *(const bf16x8*)&Wl[((ntb + nt) * 16 + c16) * 72 + ks * 32 + quad * 8];
                MFMA16(acc[nt], a, b);
            }
        }
#pragma unroll
        for (int nt = 0; nt < 4; ++nt) {
            const int col = (ntb + nt) * 16 + c16;
            const float bias = bsc[col];
#pragma unroll
            for (int r = 0; r < 4; ++r) {
                const float sc = fmaxf(acc[nt][r] + bias, 0.f);
                const int row = d0 + mtw * 16 + quad * 4 + r;
                out[(size_t)row * 128 + col] = u[nt][r] + sc;   // both >=0, final relu no-op
            }
        }
    }
}

extern "C" void kernel_launch(void* const* d_in, const int* in_sizes, int n_in,
                              void* d_out, int out_size, void* d_ws, size_t ws_size,
                              hipStream_t stream)
{
    const float* x      = (const float*)d_in[0];
    const float* pos    = (const float*)d_in[1];
    const float* W_down = (const float*)d_in[2];
    const float* b_down = (const float*)d_in[3];
    const float* W_pp1  = (const float*)d_in[4];
    const float* b_pp1  = (const float*)d_in[5];
    const float* W_att1 = (const float*)d_in[6];
    const float* b_att1 = (const float*)d_in[7];
    const float* W_g1   = (const float*)d_in[8];
    const float* b_g1   = (const float*)d_in[9];
    const float* W_pp2  = (const float*)d_in[10];
    const float* b_pp2  = (const float*)d_in[11];
    const float* W_att2 = (const float*)d_in[12];
    const float* b_att2 = (const float*)d_in[13];
    const float* W_g2   = (const float*)d_in[14];
    const float* b_g2   = (const float*)d_in[15];
    const float* W_up   = (const float*)d_in[16];
    const float* b_up   = (const float*)d_in[17];
    const float* W_sc   = (const float*)d_in[18];
    const float* b_sc   = (const float*)d_in[19];
    const int* idx1 = (const int*)d_in[20];
    const int* idx2 = (const int*)d_in[21];
    const int* src1 = (const int*)d_in[22];
    const int* src2 = (const int*)d_in[24];

    ushortT* wsw = (ushortT*)d_ws;
    ushortT* h0w   = wsw + WS_H0;
    ushortT* h1w   = wsw + WS_H1;
    ushortT* agg2w = wsw + WS_AGG2;

    k_prep <<<68, 256, 0, stream>>>(W_down, W_att1, W_g1, W_att2, W_g2, W_up, W_sc, wsw);
    k_down <<<N_FULL / 128, 256, 0, stream>>>(x, wsw, b_down, h0w);
    k_conv1<<<NN1 / 8, 256, 0, stream>>>(h0w, pos, idx1, src1,
                                         W_pp1, b_pp1, wsw, b_att1, b_g1, h1w);
    k_conv2<<<NN2 / 8, 256, 0, stream>>>(h1w, pos, idx1, idx2, src2,
                                         W_pp2, b_pp2, wsw, b_att2, agg2w);
    k_post <<<NN2 / 32, 256, 0, stream>>>(agg2w, x, idx1, idx2, wsw,
                                          b_g2, b_up, b_sc, (float*)d_out);
}

// Round 7
// 180.506 us; speedup vs baseline: 3.4320x; 1.0160x over previous
//
#include <hip/hip_runtime.h>

#define N_FULL 65536
#define NN1    16384
#define NN2    8192

typedef __attribute__((ext_vector_type(8))) short bf16x8;
typedef __attribute__((ext_vector_type(4))) float f32x4;
typedef unsigned short ushortT;

#define MFMA16(acc, a, b) acc = __builtin_amdgcn_mfma_f32_16x16x32_bf16(a, b, acc, 0, 0, 0)

#if __has_builtin(__builtin_amdgcn_cvt_pk_bf16_f32)
typedef __attribute__((ext_vector_type(2))) __bf16 bf16x2t;
static __device__ __forceinline__ unsigned pack2(float a, float b) {
    union { bf16x2t v; unsigned u; } c;
    c.v = __builtin_amdgcn_cvt_pk_bf16_f32(a, b);
    return c.u;
}
static __device__ __forceinline__ ushortT f2bf(float f) {
    union { bf16x2t v; ushortT s[2]; } c;
    c.v = __builtin_amdgcn_cvt_pk_bf16_f32(f, 0.f);
    return c.s[0];
}
#else
static __device__ __forceinline__ ushortT f2bf(float f) {
    union { float f; unsigned u; } v; v.f = f;
    unsigned r = v.u + 0x7FFFu + ((v.u >> 16) & 1u);
    return (ushortT)(r >> 16);
}
static __device__ __forceinline__ unsigned pack2(float a, float b) {
    return (unsigned)f2bf(a) | ((unsigned)f2bf(b) << 16);
}
#endif

static __device__ __forceinline__ float bfu2f(ushortT h) {
    union { unsigned u; float f; } v; v.u = (unsigned)h << 16; return v.f;
}

// ws layout (ushort units) — all byte offsets 16B-aligned
#define WS_WAT1  2304     /* [64][72]   */
#define WS_WGT1  6912     /* [64][72]   */
#define WS_WAT2  11520    /* [128][136] */
#define WS_WGT2  28928    /* [128][136] */
#define WS_WUPT  46336    /* [128][136] */
#define WS_WSCT  63744    /* [128][72]  */
#define WS_H0    73728    /* bf16 [65536][32] */
#define WS_H1    (WS_H0 + 65536u*32u)
#define WS_AGG2  (WS_H1 + 16384u*64u)

// ---------------------------------------------------------------------------
// weight transpose helper (runs in the prep-blocks of k_down)
// ---------------------------------------------------------------------------
static __device__ __forceinline__ void tpose(
    const float* __restrict__ src, ushortT* __restrict__ dst,
    int K, int N, int STR, int gid, int gs)
{
    for (int i = gid; i < K * N; i += gs) {
        const int n = i / K, k = i - n * K;
        dst[n * STR + k] = f2bf(src[(size_t)k * N + n]);
    }
}

// ---------------------------------------------------------------------------
// k_down (+prep): blocks <512: h0 = relu(x @ Wd + bd); blocks >=512: weight
// transposes for later kernels (no intra-kernel consumer -> no race).
// Down-blocks self-transpose Wd (64x32, tiny) to avoid depending on prep.
// ---------------------------------------------------------------------------
__global__ __launch_bounds__(256) void k_down(
    const float* __restrict__ x, const float* __restrict__ Wd,
    const float* __restrict__ bd,
    const float* __restrict__ Wa1, const float* __restrict__ Wg1,
    const float* __restrict__ Wa2, const float* __restrict__ Wg2,
    const float* __restrict__ Wup, const float* __restrict__ Wsc,
    ushortT* __restrict__ wsw, ushortT* __restrict__ h0w)
{
    const int t = threadIdx.x;
    if (blockIdx.x >= 512) {
        const int gid = (blockIdx.x - 512) * 256 + t, gs = 68 * 256;
        tpose(Wa1, wsw + WS_WAT1, 64, 64, 72, gid, gs);
        tpose(Wg1, wsw + WS_WGT1, 64, 64, 72, gid, gs);
        tpose(Wa2, wsw + WS_WAT2, 128, 128, 136, gid, gs);
        tpose(Wg2, wsw + WS_WGT2, 128, 128, 136, gid, gs);
        tpose(Wup, wsw + WS_WUPT, 128, 128, 136, gid, gs);
        tpose(Wsc, wsw + WS_WSCT, 64, 128, 72, gid, gs);
        return;
    }

    __shared__ __align__(16) ushortT Al[128 * 72];
    __shared__ __align__(16) ushortT Bl[32 * 72];
    const int rowBase = blockIdx.x * 128;

    {   // stage A: x rows -> bf16 LDS
        const int r = t >> 1, c0 = (t & 1) * 32;
        unsigned* dst = (unsigned*)Al + r * 36 + (c0 >> 1);
        const float* src = &x[(size_t)(rowBase + r) * 64 + c0];
#pragma unroll
        for (int j = 0; j < 32; j += 4) {
            const float4 v = *reinterpret_cast<const float4*>(src + j);
            dst[(j >> 1) + 0] = pack2(v.x, v.y);
            dst[(j >> 1) + 1] = pack2(v.z, v.w);
        }
        // stage B: Wd^T [32 n][64 k] bf16 (transpose on the fly)
        const int n = t >> 3, kc = (t & 7) * 8;
        float v[8];
#pragma unroll
        for (int j = 0; j < 8; ++j) v[j] = Wd[(size_t)(kc + j) * 32 + n];
        uint4 p;
        p.x = pack2(v[0], v[1]); p.y = pack2(v[2], v[3]);
        p.z = pack2(v[4], v[5]); p.w = pack2(v[6], v[7]);
        *(uint4*)((unsigned*)Bl + n * 36 + (kc >> 1)) = p;
    }
    __syncthreads();

    const int lane = t & 63, w = t >> 6, quad = lane >> 4, c16 = lane & 15;
    f32x4 acc[2][2];
#pragma unroll
    for (int mt = 0; mt < 2; ++mt)
#pragma unroll
        for (int nt = 0; nt < 2; ++nt)
#pragma unroll
            for (int r = 0; r < 4; ++r) acc[mt][nt][r] = 0.f;
#pragma unroll
    for (int ks = 0; ks < 2; ++ks) {
        bf16x8 a[2], b[2];
#pragma unroll
        for (int mt = 0; mt < 2; ++mt)
            a[mt] = *(const bf16x8*)&Al[(w * 32 + mt * 16 + c16) * 72 + ks * 32 + quad * 8];
#pragma unroll
        for (int nt = 0; nt < 2; ++nt)
            b[nt] = *(const bf16x8*)&Bl[(nt * 16 + c16) * 72 + ks * 32 + quad * 8];
#pragma unroll
        for (int mt = 0; mt < 2; ++mt)
#pragma unroll
            for (int nt = 0; nt < 2; ++nt) MFMA16(acc[mt][nt], a[mt], b[nt]);
    }
#pragma unroll
    for (int nt = 0; nt < 2; ++nt) {
        const int col = nt * 16 + c16;
        const float bias = bd[col];
#pragma unroll
        for (int mt = 0; mt < 2; ++mt)
#pragma unroll
            for (int r = 0; r < 4; ++r) {
                const int row = rowBase + w * 32 + mt * 16 + quad * 4 + r;
                h0w[(size_t)row * 32 + col] = f2bf(fmaxf(acc[mt][nt][r] + bias, 0.f));
            }
    }
}

// ---------------------------------------------------------------------------
// k_conv1: 8 nodes/block; F=[128 edges][64 ch] bf16 in LDS; Watt1^T/Wg1^T
// B-fragments read DIRECTLY from global (L2-hot) — no LDS weight staging.
// ---------------------------------------------------------------------------
__global__ __launch_bounds__(256) void k_conv1(
    const ushortT* __restrict__ h0w, const float* __restrict__ pos,
    const int* __restrict__ idx1, const int* __restrict__ src1,
    const float* __restrict__ Wpp, const float* __restrict__ bpp,
    const ushortT* __restrict__ wsw, const float* __restrict__ batt,
    const float* __restrict__ bg, ushortT* __restrict__ h1w)
{
    __shared__ __align__(16) ushortT Fl[128 * 72];    // 18 KB
    __shared__ __align__(16) ushortT A2ls[16 * 72];   // 2.3 KB
    __shared__ float Pl[352];                         // Wpp1 [10][32] + bpp1[32]
    const int t = threadIdx.x;
    const int d0 = blockIdx.x * 8;

    for (int i = t; i < 352; i += 256) Pl[i] = (i < 320) ? Wpp[i] : bpp[i - 320];
    for (int i = t; i < 288; i += 256) ((unsigned*)A2ls)[288 + i] = 0;  // pad rows 8..15

    {   // build F: 2 threads/edge
        const int e = t >> 1, half = t & 1;
        const int g = e >> 4;
        const int s = src1[(d0 + g) * 16 + (e & 15)];
        const uint4* srcp = (const uint4*)((const unsigned*)h0w + (size_t)s * 16 + half * 8);
        uint4* dstp = (uint4*)((unsigned*)Fl + e * 36 + half * 8);
        dstp[0] = srcp[0];
        dstp[1] = srcp[1];

        const int pin = idx1[d0 + g];
        const float pix = pos[pin * 3 + 0], piy = pos[pin * 3 + 1], piz = pos[pin * 3 + 2];
        const float pjx = pos[s * 3 + 0],  pjy = pos[s * 3 + 1],  pjz = pos[s * 3 + 2];
        const float vx = pix - pjx, vy = piy - pjy, vz = piz - pjz;
        const float dij = sqrtf(vx * vx + vy * vy + vz * vz);
        const float rel[10] = {pix, piy, piz, pjx, pjy, pjz, vx, vy, vz, dij};
        __syncthreads();    // Pl ready
        const int c0 = half * 16;
#pragma unroll
        for (int c = 0; c < 16; c += 2) {
            float a0 = Pl[320 + c0 + c], a1 = Pl[320 + c0 + c + 1];
#pragma unroll
            for (int i = 0; i < 10; ++i) {
                a0 += rel[i] * Pl[i * 32 + c0 + c];
                a1 += rel[i] * Pl[i * 32 + c0 + c + 1];
            }
            ((unsigned*)Fl)[(e * 72 + 32 + c0 + c) >> 1] = pack2(fmaxf(a0, 0.f), fmaxf(a1, 0.f));
        }
    }
    __syncthreads();

    const int lane = t & 63, w = t >> 6, quad = lane >> 4, c16 = lane & 15;
    const ushortT* WB = wsw + WS_WAT1;    // Watt1^T [64][72], B-frags from global
    f32x4 acc[2][4];
#pragma unroll
    for (int mt = 0; mt < 2; ++mt)
#pragma unroll
        for (int nt = 0; nt < 4; ++nt)
#pragma unroll
            for (int r = 0; r < 4; ++r) acc[mt][nt][r] = 0.f;
#pragma unroll
    for (int ks = 0; ks < 2; ++ks) {
        bf16x8 a[2];
#pragma unroll
        for (int mt = 0; mt < 2; ++mt)
            a[mt] = *(const bf16x8*)&Fl[(w * 32 + mt * 16 + c16) * 72 + ks * 32 + quad * 8];
#pragma unroll
        for (int nt = 0; nt < 4; ++nt) {
            const bf16x8 b = *(const bf16x8*)&WB[(nt * 16 + c16) * 72 + ks * 32 + quad * 8];
#pragma unroll
            for (int mt = 0; mt < 2; ++mt) MFMA16(acc[mt][nt], a[mt], b);
        }
    }
    float bcol[4];
#pragma unroll
    for (int nt = 0; nt < 4; ++nt) bcol[nt] = batt[nt * 16 + c16];

#pragma unroll
    for (int mt = 0; mt < 2; ++mt) {
#pragma unroll
        for (int nt = 0; nt < 4; ++nt)
#pragma unroll
            for (int r = 0; r < 4; ++r)
                acc[mt][nt][r] = fmaxf(acc[mt][nt][r] + bcol[nt], 0.f);
        float rs[4];
#pragma unroll
        for (int r = 0; r < 4; ++r) {
            float mx = acc[mt][0][r];
#pragma unroll
            for (int nt = 1; nt < 4; ++nt) mx = fmaxf(mx, acc[mt][nt][r]);
            mx = fmaxf(mx, __shfl_xor(mx, 1));
            mx = fmaxf(mx, __shfl_xor(mx, 2));
            mx = fmaxf(mx, __shfl_xor(mx, 4));
            mx = fmaxf(mx, __shfl_xor(mx, 8));
            float sm = 0.f;
#pragma unroll
            for (int nt = 0; nt < 4; ++nt) {
                acc[mt][nt][r] = __expf(acc[mt][nt][r] - mx);
                sm += acc[mt][nt][r];
            }
            sm += __shfl_xor(sm, 1);
            sm += __shfl_xor(sm, 2);
            sm += __shfl_xor(sm, 4);
            sm += __shfl_xor(sm, 8);
            rs[r] = 1.f / sm;
        }
#pragma unroll
        for (int nt = 0; nt < 4; ++nt) {
            float v = 0.f;
#pragma unroll
            for (int r = 0; r < 4; ++r) {
                const float fv = bfu2f(Fl[(w * 32 + mt * 16 + quad * 4 + r) * 72 + nt * 16 + c16]);
                v += acc[mt][nt][r] * rs[r] * fv;
            }
            v += __shfl_xor(v, 16);
            v += __shfl_xor(v, 32);
            if (lane < 16)
                A2ls[(w * 2 + mt) * 72 + nt * 16 + c16] = f2bf(v);
        }
    }
    __syncthreads();

    // ---- fused global_nn: h1 = relu(agg @ Wg1 + bg1); wave w = N-tile w ----
    {
        const ushortT* GB = wsw + WS_WGT1;
        f32x4 acc2 = {0.f, 0.f, 0.f, 0.f};
#pragma unroll
        for (int ks = 0; ks < 2; ++ks) {
            const bf16x8 a = *(const bf16x8*)&A2ls[c16 * 72 + ks * 32 + quad * 8];
            const bf16x8 b = *(const bf16x8*)&GB[(w * 16 + c16) * 72 + ks * 32 + quad * 8];
            MFMA16(acc2, a, b);
        }
        const int col = w * 16 + c16;
        const float bias = bg[col];
        if (quad < 2) {     // rows 0..7 valid
#pragma unroll
            for (int r = 0; r < 4; ++r) {
                const int row = quad * 4 + r;
                h1w[(size_t)(d0 + row) * 64 + col] = f2bf(fmaxf(acc2[r] + bias, 0.f));
            }
        }
    }
}

// ---------------------------------------------------------------------------
// k_conv2: 8 nodes/block, F=[128 edges][128 ch] bf16; Watt2^T B-frags from
// global. LDS = F + Pl only (~38 KB) -> 4 blocks/CU.
// ---------------------------------------------------------------------------
__global__ __launch_bounds__(256) void k_conv2(
    const ushortT* __restrict__ h1w, const float* __restrict__ pos,
    const int* __restrict__ idx1, const int* __restrict__ idx2,
    const int* __restrict__ src2,
    const float* __restrict__ Wpp, const float* __restrict__ bpp,
    const ushortT* __restrict__ wsw, const float* __restrict__ batt,
    ushortT* __restrict__ agg2w)
{
    __shared__ __align__(16) ushortT Fl[128 * 136];   // 34.8 KB
    __shared__ float Pl[704];                         // Wpp2 [10][64] + bpp2[64]
    const int t = threadIdx.x;
    const int d0 = blockIdx.x * 8;

    for (int i = t; i < 704; i += 256) Pl[i] = (i < 640) ? Wpp[i] : bpp[i - 640];

    {   // build F: 2 threads/edge
        const int e = t >> 1, half = t & 1;
        const int g = e >> 4;
        const int s = src2[(d0 + g) * 16 + (e & 15)];
        const uint4* srcp = (const uint4*)((const unsigned*)h1w + (size_t)s * 32 + half * 16);
        uint4* dstp = (uint4*)((unsigned*)Fl + e * 68 + half * 16);
#pragma unroll
        for (int j = 0; j < 4; ++j) dstp[j] = srcp[j];

        const int pin = idx1[idx2[d0 + g]];
        const int sn = idx1[s];
        const float pix = pos[pin * 3 + 0], piy = pos[pin * 3 + 1], piz = pos[pin * 3 + 2];
        const float pjx = pos[sn * 3 + 0],  pjy = pos[sn * 3 + 1],  pjz = pos[sn * 3 + 2];
        const float vx = pix - pjx, vy = piy - pjy, vz = piz - pjz;
        const float dij = sqrtf(vx * vx + vy * vy + vz * vz);
        const float rel[10] = {pix, piy, piz, pjx, pjy, pjz, vx, vy, vz, dij};
        __syncthreads();    // Pl ready
        const int c0 = half * 32;
#pragma unroll
        for (int c = 0; c < 32; c += 2) {
            float a0 = Pl[640 + c0 + c], a1 = Pl[640 + c0 + c + 1];
#pragma unroll
            for (int i = 0; i < 10; ++i) {
                a0 += rel[i] * Pl[i * 64 + c0 + c];
                a1 += rel[i] * Pl[i * 64 + c0 + c + 1];
            }
            ((unsigned*)Fl)[(e * 136 + 64 + c0 + c) >> 1] = pack2(fmaxf(a0, 0.f), fmaxf(a1, 0.f));
        }
    }
    __syncthreads();

    const int lane = t & 63, w = t >> 6, quad = lane >> 4, c16 = lane & 15;
    const ushortT* WB = wsw + WS_WAT2;    // Watt2^T [128][136]
    f32x4 acc[2][8];
#pragma unroll
    for (int mt = 0; mt < 2; ++mt)
#pragma unroll
        for (int nt = 0; nt < 8; ++nt)
#pragma unroll
            for (int r = 0; r < 4; ++r) acc[mt][nt][r] = 0.f;
#pragma unroll
    for (int ks = 0; ks < 4; ++ks) {
        bf16x8 a[2];
#pragma unroll
        for (int mt = 0; mt < 2; ++mt)
            a[mt] = *(const bf16x8*)&Fl[(w * 32 + mt * 16 + c16) * 136 + ks * 32 + quad * 8];
#pragma unroll
        for (int nt = 0; nt < 8; ++nt) {
            const bf16x8 b = *(const bf16x8*)&WB[(nt * 16 + c16) * 136 + ks * 32 + quad * 8];
#pragma unroll
            for (int mt = 0; mt < 2; ++mt) MFMA16(acc[mt][nt], a[mt], b);
        }
    }
    float bcol[8];
#pragma unroll
    for (int nt = 0; nt < 8; ++nt) bcol[nt] = batt[nt * 16 + c16];

#pragma unroll
    for (int mt = 0; mt < 2; ++mt) {
#pragma unroll
        for (int nt = 0; nt < 8; ++nt)
#pragma unroll
            for (int r = 0; r < 4; ++r)
                acc[mt][nt][r] = fmaxf(acc[mt][nt][r] + bcol[nt], 0.f);
        float rs[4];
#pragma unroll
        for (int r = 0; r < 4; ++r) {
            float mx = acc[mt][0][r];
#pragma unroll
            for (int nt = 1; nt < 8; ++nt) mx = fmaxf(mx, acc[mt][nt][r]);
            mx = fmaxf(mx, __shfl_xor(mx, 1));
            mx = fmaxf(mx, __shfl_xor(mx, 2));
            mx = fmaxf(mx, __shfl_xor(mx, 4));
            mx = fmaxf(mx, __shfl_xor(mx, 8));
            float sm = 0.f;
#pragma unroll
            for (int nt = 0; nt < 8; ++nt) {
                acc[mt][nt][r] = __expf(acc[mt][nt][r] - mx);
                sm += acc[mt][nt][r];
            }
            sm += __shfl_xor(sm, 1);
            sm += __shfl_xor(sm, 2);
            sm += __shfl_xor(sm, 4);
            sm += __shfl_xor(sm, 8);
            rs[r] = 1.f / sm;
        }
#pragma unroll
        for (int nt = 0; nt < 8; ++nt) {
            float v = 0.f;
#pragma unroll
            for (int r = 0; r < 4; ++r) {
                const float fv = bfu2f(Fl[(w * 32 + mt * 16 + quad * 4 + r) * 136 + nt * 16 + c16]);
                v += acc[mt][nt][r] * rs[r] * fv;
            }
            v += __shfl_xor(v, 16);
            v += __shfl_xor(v, 32);
            if (lane < 16)
                agg2w[(size_t)(d0 + w * 2 + mt) * 128 + nt * 16 + c16] = f2bf(v);
        }
    }
}

// ---------------------------------------------------------------------------
// k_post: 32 nodes/block (256 blocks); all weight B-frags from global.
// h2=relu(agg2@Wg2+bg2); u=relu(h2@Wup+bup); sc=relu(x2@Wsc+bsc); out=u+sc.
// ---------------------------------------------------------------------------
__global__ __launch_bounds__(256) void k_post(
    const ushortT* __restrict__ agg2w, const float* __restrict__ x,
    const int* __restrict__ idx1, const int* __restrict__ idx2,
    const ushortT* __restrict__ wsw,
    const float* __restrict__ bg, const float* __restrict__ bup,
    const float* __restrict__ bsc, float* __restrict__ out)
{
    __shared__ __align__(16) ushortT Al[32 * 136];
    __shared__ __align__(16) ushortT Bl[32 * 136];
    __shared__ __align__(16) ushortT A2[32 * 72];
    const int t = threadIdx.x;
    const int d0 = blockIdx.x * 32;

    // stage agg2 rows (uint4: 16 per row)
    for (int i = t; i < 512; i += 256) {
        const int r = i >> 4, j = i & 15;
        ((uint4*)((unsigned*)Al + r * 68))[j] =
            ((const uint4*)((const unsigned*)agg2w + (size_t)(d0 + r) * 64))[j];
    }
    // stage shortcut x rows (gather + cvt): 8 threads/row, 8 floats each
    {
        const int r = t >> 3, q = t & 7;
        const int pin = idx1[idx2[d0 + r]];
        const float* src = &x[(size_t)pin * 64 + q * 8];
        unsigned* dst = (unsigned*)A2 + r * 36 + q * 4;
#pragma unroll
        for (int j = 0; j < 4; ++j) {
            const float2 v = *reinterpret_cast<const float2*>(src + j * 2);
            dst[j] = pack2(v.x, v.y);
        }
    }
    __syncthreads();

    const int lane = t & 63, w = t >> 6, quad = lane >> 4, c16 = lane & 15;
    const int mtw = w >> 1;            // 16-row tile base
    const int ntb = (w & 1) * 4;       // n-tiles ntb..ntb+3

    // ---- GEMM1: h2 = relu(agg2 @ Wg2 + bg2) -> Bl ----
    {
        const ushortT* WB = wsw + WS_WGT2;
        f32x4 acc[4];
#pragma unroll
        for (int nt = 0; nt < 4; ++nt)
#pragma unroll
            for (int r = 0; r < 4; ++r) acc[nt][r] = 0.f;
#pragma unroll
        for (int ks = 0; ks < 4; ++ks) {
            const bf16x8 a = *(const bf16x8*)&Al[(mtw * 16 + c16) * 136 + ks * 32 + quad * 8];
#pragma unroll
            for (int nt = 0; nt < 4; ++nt) {
                const bf16x8 b = *(const bf16x8*)&WB[((ntb + nt) * 16 + c16) * 136 + ks * 32 + quad * 8];
                MFMA16(acc[nt], a, b);
            }
        }
#pragma unroll
        for (int nt = 0; nt < 4; ++nt) {
            const int col = (ntb + nt) * 16 + c16;
            const float bias = bg[col];
#pragma unroll
            for (int r = 0; r < 4; ++r)
                Bl[(mtw * 16 + quad * 4 + r) * 136 + col] = f2bf(fmaxf(acc[nt][r] + bias, 0.f));
        }
    }
    __syncthreads();

    // ---- GEMM2: u = relu(h2 @ Wup + bup), keep in regs ----
    f32x4 u[4];
    {
        const ushortT* WB = wsw + WS_WUPT;
#pragma unroll
        for (int nt = 0; nt < 4; ++nt)
#pragma unroll
            for (int r = 0; r < 4; ++r) u[nt][r] = 0.f;
#pragma unroll
        for (int ks = 0; ks < 4; ++ks) {
            const bf16x8 a = *(const bf16x8*)&Bl[(mtw * 16 + c16) * 136 + ks * 32 + quad * 8];
#pragma unroll
            for (int nt = 0; nt < 4; ++nt) {
                const bf16x8 b = *(const bf16x8*)&WB[((ntb + nt) * 16 + c16) * 136 + ks * 32 + quad * 8];
                MFMA16(u[nt], a, b);
            }
        }
#pragma unroll
        for (int nt = 0; nt < 4; ++nt) {
            const float bias = bup[(ntb + nt) * 16 + c16];
#pragma unroll
            for (int r = 0; r < 4; ++r) u[nt][r] = fmaxf(u[nt][r] + bias, 0.f);
        }
    }

    // ---- GEMM3: sc = relu(x2 @ Wsc + bsc); out = u + sc ----
    {
        const ushortT* WB = wsw + WS_WSCT;   // [128][72]
        f32x4 acc[4];
#pragma unroll
        for (int nt = 0; nt < 4; ++nt)
#pragma unroll
            for (int r = 0; r < 4; ++r) acc[nt][r] = 0.f;
#pragma unroll
        for (int ks = 0; ks < 2; ++ks) {
            const bf16x8 a = *(const bf16x8*)&A2[(mtw * 16 + c16) * 72 + ks * 32 + quad * 8];
#pragma unroll
            for (int nt = 0; nt < 4; ++nt) {
                const bf16x8 b = *(const bf16x8*)&WB[((ntb + nt) * 16 + c16) * 72 + ks * 32 + quad * 8];
                MFMA16(acc[nt], a, b);
            }
        }
#pragma unroll
        for (int nt = 0; nt < 4; ++nt) {
            const int col = (ntb + nt) * 16 + c16;
            const float bias = bsc[col];
#pragma unroll
            for (int r = 0; r < 4; ++r) {
                const float sc = fmaxf(acc[nt][r] + bias, 0.f);
                const int row = d0 + mtw * 16 + quad * 4 + r;
                out[(size_t)row * 128 + col] = u[nt][r] + sc;   // both >=0, relu no-op
            }
        }
    }
}

extern "C" void kernel_launch(void* const* d_in, const int* in_sizes, int n_in,
                              void* d_out, int out_size, void* d_ws, size_t ws_size,
                              hipStream_t stream)
{
    const float* x      = (const float*)d_in[0];
    const float* pos    = (const float*)d_in[1];
    const float* W_down = (const float*)d_in[2];
    const float* b_down = (const float*)d_in[3];
    const float* W_pp1  = (const float*)d_in[4];
    const float* b_pp1  = (const float*)d_in[5];
    const float* W_att1 = (const float*)d_in[6];
    const float* b_att1 = (const float*)d_in[7];
    const float* W_g1   = (const float*)d_in[8];
    const float* b_g1   = (const float*)d_in[9];
    const float* W_pp2  = (const float*)d_in[10];
    const float* b_pp2  = (const float*)d_in[11];
    const float* W_att2 = (const float*)d_in[12];
    const float* b_att2 = (const float*)d_in[13];
    const float* W_g2   = (const float*)d_in[14];
    const float* b_g2   = (const float*)d_in[15];
    const float* W_up   = (const float*)d_in[16];
    const float* b_up   = (const float*)d_in[17];
    const float* W_sc   = (const float*)d_in[18];
    const float* b_sc   = (const float*)d_in[19];
    const int* idx1 = (const int*)d_in[20];
    const int* idx2 = (const int*)d_in[21];
    const int* src1 = (const int*)d_in[22];
    const int* src2 = (const int*)d_in[24];

    ushortT* wsw = (ushortT*)d_ws;
    ushortT* h0w   = wsw + WS_H0;
    ushortT* h1w   = wsw + WS_H1;
    ushortT* agg2w = wsw + WS_AGG2;

    k_down <<<512 + 68, 256, 0, stream>>>(x, W_down, b_down,
                                          W_att1, W_g1, W_att2, W_g2, W_up, W_sc,
                                          wsw, h0w);
    k_conv1<<<NN1 / 8, 256, 0, stream>>>(h0w, pos, idx1, src1,
                                         W_pp1, b_pp1, wsw, b_att1, b_g1, h1w);
    k_conv2<<<NN2 / 8, 256, 0, stream>>>(h1w, pos, idx1, idx2, src2,
                                         W_pp2, b_pp2, wsw, b_att2, agg2w);
    k_post <<<NN2 / 32, 256, 0, stream>>>(agg2w, x, idx1, idx2, wsw,
                                          b_g2, b_up, b_sc, (float*)d_out);
}

// Round 8
// 177.140 us; speedup vs baseline: 3.4972x; 1.0190x over previous
//
#include <hip/hip_runtime.h>

#define N_FULL 65536
#define NN1    16384
#define NN2    8192

typedef __attribute__((ext_vector_type(8))) short bf16x8;
typedef __attribute__((ext_vector_type(4))) float f32x4;
typedef unsigned short ushortT;

#define MFMA16(acc, a, b) acc = __builtin_amdgcn_mfma_f32_16x16x32_bf16(a, b, acc, 0, 0, 0)

#if __has_builtin(__builtin_amdgcn_cvt_pk_bf16_f32)
typedef __attribute__((ext_vector_type(2))) __bf16 bf16x2t;
static __device__ __forceinline__ unsigned pack2(float a, float b) {
    union { bf16x2t v; unsigned u; } c;
    c.v = __builtin_amdgcn_cvt_pk_bf16_f32(a, b);
    return c.u;
}
static __device__ __forceinline__ ushortT f2bf(float f) {
    union { bf16x2t v; ushortT s[2]; } c;
    c.v = __builtin_amdgcn_cvt_pk_bf16_f32(f, 0.f);
    return c.s[0];
}
#else
static __device__ __forceinline__ ushortT f2bf(float f) {
    union { float f; unsigned u; } v; v.f = f;
    unsigned r = v.u + 0x7FFFu + ((v.u >> 16) & 1u);
    return (ushortT)(r >> 16);
}
static __device__ __forceinline__ unsigned pack2(float a, float b) {
    return (unsigned)f2bf(a) | ((unsigned)f2bf(b) << 16);
}
#endif

static __device__ __forceinline__ float bfu2f(ushortT h) {
    union { unsigned u; float f; } v; v.u = (unsigned)h << 16; return v.f;
}

// ws layout (ushort units) — all byte offsets 16B-aligned
#define WS_WAT1  2304     /* [64][72]   */
#define WS_WGT1  6912     /* [64][72]   */
#define WS_WAT2  11520    /* [128][136] */
#define WS_WGT2  28928    /* [128][136] */
#define WS_WUPT  46336    /* [128][136] */
#define WS_WSCT  63744    /* [128][72]  */
#define WS_H0    73728    /* bf16 [65536][32] */
#define WS_H1    (WS_H0 + 65536u*32u)

// softmax fixed shift: softmax(a) == softmax(a - C); scores are relu'd O(10)
#define SMAX_SHIFT 24.0f

// ---------------------------------------------------------------------------
// weight transpose helper (runs in the prep-blocks of k_down)
// ---------------------------------------------------------------------------
static __device__ __forceinline__ void tpose(
    const float* __restrict__ src, ushortT* __restrict__ dst,
    int K, int N, int STR, int gid, int gs)
{
    for (int i = gid; i < K * N; i += gs) {
        const int n = i / K, k = i - n * K;
        dst[n * STR + k] = f2bf(src[(size_t)k * N + n]);
    }
}

// ---------------------------------------------------------------------------
// k_down (+prep): blocks <512: h0 = relu(x @ Wd + bd); blocks >=512: weight
// transposes for later kernels.
// ---------------------------------------------------------------------------
__global__ __launch_bounds__(256) void k_down(
    const float* __restrict__ x, const float* __restrict__ Wd,
    const float* __restrict__ bd,
    const float* __restrict__ Wa1, const float* __restrict__ Wg1,
    const float* __restrict__ Wa2, const float* __restrict__ Wg2,
    const float* __restrict__ Wup, const float* __restrict__ Wsc,
    ushortT* __restrict__ wsw, ushortT* __restrict__ h0w)
{
    const int t = threadIdx.x;
    if (blockIdx.x >= 512) {
        const int gid = (blockIdx.x - 512) * 256 + t, gs = 68 * 256;
        tpose(Wa1, wsw + WS_WAT1, 64, 64, 72, gid, gs);
        tpose(Wg1, wsw + WS_WGT1, 64, 64, 72, gid, gs);
        tpose(Wa2, wsw + WS_WAT2, 128, 128, 136, gid, gs);
        tpose(Wg2, wsw + WS_WGT2, 128, 128, 136, gid, gs);
        tpose(Wup, wsw + WS_WUPT, 128, 128, 136, gid, gs);
        tpose(Wsc, wsw + WS_WSCT, 64, 128, 72, gid, gs);
        return;
    }

    __shared__ __align__(16) ushortT Al[128 * 72];
    __shared__ __align__(16) ushortT Bl[32 * 72];
    const int rowBase = blockIdx.x * 128;

    {   // stage A: x rows -> bf16 LDS
        const int r = t >> 1, c0 = (t & 1) * 32;
        unsigned* dst = (unsigned*)Al + r * 36 + (c0 >> 1);
        const float* src = &x[(size_t)(rowBase + r) * 64 + c0];
#pragma unroll
        for (int j = 0; j < 32; j += 4) {
            const float4 v = *reinterpret_cast<const float4*>(src + j);
            dst[(j >> 1) + 0] = pack2(v.x, v.y);
            dst[(j >> 1) + 1] = pack2(v.z, v.w);
        }
        // stage B: Wd^T [32 n][64 k] bf16 (transpose on the fly)
        const int n = t >> 3, kc = (t & 7) * 8;
        float v[8];
#pragma unroll
        for (int j = 0; j < 8; ++j) v[j] = Wd[(size_t)(kc + j) * 32 + n];
        uint4 p;
        p.x = pack2(v[0], v[1]); p.y = pack2(v[2], v[3]);
        p.z = pack2(v[4], v[5]); p.w = pack2(v[6], v[7]);
        *(uint4*)((unsigned*)Bl + n * 36 + (kc >> 1)) = p;
    }
    __syncthreads();

    const int lane = t & 63, w = t >> 6, quad = lane >> 4, c16 = lane & 15;
    f32x4 acc[2][2];
#pragma unroll
    for (int mt = 0; mt < 2; ++mt)
#pragma unroll
        for (int nt = 0; nt < 2; ++nt)
#pragma unroll
            for (int r = 0; r < 4; ++r) acc[mt][nt][r] = 0.f;
#pragma unroll
    for (int ks = 0; ks < 2; ++ks) {
        bf16x8 a[2], b[2];
#pragma unroll
        for (int mt = 0; mt < 2; ++mt)
            a[mt] = *(const bf16x8*)&Al[(w * 32 + mt * 16 + c16) * 72 + ks * 32 + quad * 8];
#pragma unroll
        for (int nt = 0; nt < 2; ++nt)
            b[nt] = *(const bf16x8*)&Bl[(nt * 16 + c16) * 72 + ks * 32 + quad * 8];
#pragma unroll
        for (int mt = 0; mt < 2; ++mt)
#pragma unroll
            for (int nt = 0; nt < 2; ++nt) MFMA16(acc[mt][nt], a[mt], b[nt]);
    }
#pragma unroll
    for (int nt = 0; nt < 2; ++nt) {
        const int col = nt * 16 + c16;
        const float bias = bd[col];
#pragma unroll
        for (int mt = 0; mt < 2; ++mt)
#pragma unroll
            for (int r = 0; r < 4; ++r) {
                const int row = rowBase + w * 32 + mt * 16 + quad * 4 + r;
                h0w[(size_t)row * 32 + col] = f2bf(fmaxf(acc[mt][nt][r] + bias, 0.f));
            }
    }
}

// ---------------------------------------------------------------------------
// k_conv1: 8 nodes/block; F=[128 edges][64 ch] bf16 in LDS; Watt1^T/Wg1^T
// B-fragments direct from global (L2-hot). Fixed-shift softmax.
// ---------------------------------------------------------------------------
__global__ __launch_bounds__(256) void k_conv1(
    const ushortT* __restrict__ h0w, const float* __restrict__ pos,
    const int* __restrict__ idx1, const int* __restrict__ src1,
    const float* __restrict__ Wpp, const float* __restrict__ bpp,
    const ushortT* __restrict__ wsw, const float* __restrict__ batt,
    const float* __restrict__ bg, ushortT* __restrict__ h1w)
{
    __shared__ __align__(16) ushortT Fl[128 * 72];    // 18 KB
    __shared__ __align__(16) ushortT A2ls[16 * 72];   // 2.3 KB
    __shared__ float Pl[352];                         // Wpp1 [10][32] + bpp1[32]
    const int t = threadIdx.x;
    const int d0 = blockIdx.x * 8;

    for (int i = t; i < 352; i += 256) Pl[i] = (i < 320) ? Wpp[i] : bpp[i - 320];
    for (int i = t; i < 288; i += 256) ((unsigned*)A2ls)[288 + i] = 0;  // pad rows 8..15

    {   // build F: 2 threads/edge
        const int e = t >> 1, half = t & 1;
        const int g = e >> 4;
        const int s = src1[(d0 + g) * 16 + (e & 15)];
        const uint4* srcp = (const uint4*)((const unsigned*)h0w + (size_t)s * 16 + half * 8);
        uint4* dstp = (uint4*)((unsigned*)Fl + e * 36 + half * 8);
        dstp[0] = srcp[0];
        dstp[1] = srcp[1];

        const int pin = idx1[d0 + g];
        const float pix = pos[pin * 3 + 0], piy = pos[pin * 3 + 1], piz = pos[pin * 3 + 2];
        const float pjx = pos[s * 3 + 0],  pjy = pos[s * 3 + 1],  pjz = pos[s * 3 + 2];
        const float vx = pix - pjx, vy = piy - pjy, vz = piz - pjz;
        const float dij = sqrtf(vx * vx + vy * vy + vz * vz);
        const float rel[10] = {pix, piy, piz, pjx, pjy, pjz, vx, vy, vz, dij};
        __syncthreads();    // Pl ready
        const int c0 = half * 16;
#pragma unroll
        for (int c = 0; c < 16; c += 2) {
            float a0 = Pl[320 + c0 + c], a1 = Pl[320 + c0 + c + 1];
#pragma unroll
            for (int i = 0; i < 10; ++i) {
                a0 += rel[i] * Pl[i * 32 + c0 + c];
                a1 += rel[i] * Pl[i * 32 + c0 + c + 1];
            }
            ((unsigned*)Fl)[(e * 72 + 32 + c0 + c) >> 1] = pack2(fmaxf(a0, 0.f), fmaxf(a1, 0.f));
        }
    }
    __syncthreads();

    const int lane = t & 63, w = t >> 6, quad = lane >> 4, c16 = lane & 15;
    const ushortT* WB = wsw + WS_WAT1;    // Watt1^T [64][72]
    f32x4 acc[2][4];
#pragma unroll
    for (int mt = 0; mt < 2; ++mt)
#pragma unroll
        for (int nt = 0; nt < 4; ++nt)
#pragma unroll
            for (int r = 0; r < 4; ++r) acc[mt][nt][r] = 0.f;
#pragma unroll
    for (int ks = 0; ks < 2; ++ks) {
        bf16x8 a[2];
#pragma unroll
        for (int mt = 0; mt < 2; ++mt)
            a[mt] = *(const bf16x8*)&Fl[(w * 32 + mt * 16 + c16) * 72 + ks * 32 + quad * 8];
#pragma unroll
        for (int nt = 0; nt < 4; ++nt) {
            const bf16x8 b = *(const bf16x8*)&WB[(nt * 16 + c16) * 72 + ks * 32 + quad * 8];
#pragma unroll
            for (int mt = 0; mt < 2; ++mt) MFMA16(acc[mt][nt], a[mt], b);
        }
    }
    float bcol[4];
#pragma unroll
    for (int nt = 0; nt < 4; ++nt) bcol[nt] = batt[nt * 16 + c16];

#pragma unroll
    for (int mt = 0; mt < 2; ++mt) {
        float rs[4];
#pragma unroll
        for (int r = 0; r < 4; ++r) {
            float sm = 0.f;
#pragma unroll
            for (int nt = 0; nt < 4; ++nt) {
                const float a = fmaxf(acc[mt][nt][r] + bcol[nt], 0.f);
                acc[mt][nt][r] = __expf(a - SMAX_SHIFT);
                sm += acc[mt][nt][r];
            }
            sm += __shfl_xor(sm, 1);
            sm += __shfl_xor(sm, 2);
            sm += __shfl_xor(sm, 4);
            sm += __shfl_xor(sm, 8);
            rs[r] = 1.f / sm;
        }
#pragma unroll
        for (int nt = 0; nt < 4; ++nt) {
            float v = 0.f;
#pragma unroll
            for (int r = 0; r < 4; ++r) {
                const float fv = bfu2f(Fl[(w * 32 + mt * 16 + quad * 4 + r) * 72 + nt * 16 + c16]);
                v += acc[mt][nt][r] * rs[r] * fv;
            }
            v += __shfl_xor(v, 16);
            v += __shfl_xor(v, 32);
            if (lane < 16)
                A2ls[(w * 2 + mt) * 72 + nt * 16 + c16] = f2bf(v);
        }
    }
    __syncthreads();

    // ---- fused global_nn: h1 = relu(agg @ Wg1 + bg1); wave w = N-tile w ----
    {
        const ushortT* GB = wsw + WS_WGT1;
        f32x4 acc2 = {0.f, 0.f, 0.f, 0.f};
#pragma unroll
        for (int ks = 0; ks < 2; ++ks) {
            const bf16x8 a = *(const bf16x8*)&A2ls[c16 * 72 + ks * 32 + quad * 8];
            const bf16x8 b = *(const bf16x8*)&GB[(w * 16 + c16) * 72 + ks * 32 + quad * 8];
            MFMA16(acc2, a, b);
        }
        const int col = w * 16 + c16;
        const float bias = bg[col];
        if (quad < 2) {     // rows 0..7 valid
#pragma unroll
            for (int r = 0; r < 4; ++r) {
                const int row = quad * 4 + r;
                h1w[(size_t)(d0 + row) * 64 + col] = f2bf(fmaxf(acc2[r] + bias, 0.f));
            }
        }
    }
}

// ---------------------------------------------------------------------------
// k_conv2f: 8 nodes/block; conv2 attention + FUSED post (3 chained GEMMs at
// M=16, 8 valid rows). MFMA pad-row garbage only corrupts discarded D rows.
// ---------------------------------------------------------------------------
__global__ __launch_bounds__(256) void k_conv2f(
    const ushortT* __restrict__ h1w, const float* __restrict__ pos,
    const float* __restrict__ x,
    const int* __restrict__ idx1, const int* __restrict__ idx2,
    const int* __restrict__ src2,
    const float* __restrict__ Wpp, const float* __restrict__ bpp,
    const ushortT* __restrict__ wsw, const float* __restrict__ batt,
    const float* __restrict__ bg, const float* __restrict__ bup,
    const float* __restrict__ bsc, float* __restrict__ out)
{
    __shared__ __align__(16) ushortT Fl[128 * 136];   // 34.8 KB
    __shared__ __align__(16) ushortT AGG[16 * 136];   // 4.3 KB (rows 8..15 pad)
    __shared__ __align__(16) ushortT H2[16 * 136];    // 4.3 KB
    __shared__ float Pl[704];                         // Wpp2 [10][64] + bpp2[64]
    const int t = threadIdx.x;
    const int d0 = blockIdx.x * 8;

    for (int i = t; i < 704; i += 256) Pl[i] = (i < 640) ? Wpp[i] : bpp[i - 640];

    {   // build F: 2 threads/edge
        const int e = t >> 1, half = t & 1;
        const int g = e >> 4;
        const int s = src2[(d0 + g) * 16 + (e & 15)];
        const uint4* srcp = (const uint4*)((const unsigned*)h1w + (size_t)s * 32 + half * 16);
        uint4* dstp = (uint4*)((unsigned*)Fl + e * 68 + half * 16);
#pragma unroll
        for (int j = 0; j < 4; ++j) dstp[j] = srcp[j];

        const int pin = idx1[idx2[d0 + g]];
        const int sn = idx1[s];
        const float pix = pos[pin * 3 + 0], piy = pos[pin * 3 + 1], piz = pos[pin * 3 + 2];
        const float pjx = pos[sn * 3 + 0],  pjy = pos[sn * 3 + 1],  pjz = pos[sn * 3 + 2];
        const float vx = pix - pjx, vy = piy - pjy, vz = piz - pjz;
        const float dij = sqrtf(vx * vx + vy * vy + vz * vz);
        const float rel[10] = {pix, piy, piz, pjx, pjy, pjz, vx, vy, vz, dij};
        __syncthreads();    // Pl ready
        const int c0 = half * 32;
#pragma unroll
        for (int c = 0; c < 32; c += 2) {
            float a0 = Pl[640 + c0 + c], a1 = Pl[640 + c0 + c + 1];
#pragma unroll
            for (int i = 0; i < 10; ++i) {
                a0 += rel[i] * Pl[i * 64 + c0 + c];
                a1 += rel[i] * Pl[i * 64 + c0 + c + 1];
            }
            ((unsigned*)Fl)[(e * 136 + 64 + c0 + c) >> 1] = pack2(fmaxf(a0, 0.f), fmaxf(a1, 0.f));
        }
    }
    __syncthreads();

    const int lane = t & 63, w = t >> 6, quad = lane >> 4, c16 = lane & 15;
    const ushortT* WB = wsw + WS_WAT2;    // Watt2^T [128][136]
    f32x4 acc[2][8];
#pragma unroll
    for (int mt = 0; mt < 2; ++mt)
#pragma unroll
        for (int nt = 0; nt < 8; ++nt)
#pragma unroll
            for (int r = 0; r < 4; ++r) acc[mt][nt][r] = 0.f;
#pragma unroll
    for (int ks = 0; ks < 4; ++ks) {
        bf16x8 a[2];
#pragma unroll
        for (int mt = 0; mt < 2; ++mt)
            a[mt] = *(const bf16x8*)&Fl[(w * 32 + mt * 16 + c16) * 136 + ks * 32 + quad * 8];
#pragma unroll
        for (int nt = 0; nt < 8; ++nt) {
            const bf16x8 b = *(const bf16x8*)&WB[(nt * 16 + c16) * 136 + ks * 32 + quad * 8];
#pragma unroll
            for (int mt = 0; mt < 2; ++mt) MFMA16(acc[mt][nt], a[mt], b);
        }
    }
    float bcol[8];
#pragma unroll
    for (int nt = 0; nt < 8; ++nt) bcol[nt] = batt[nt * 16 + c16];

#pragma unroll
    for (int mt = 0; mt < 2; ++mt) {
        float rs[4];
#pragma unroll
        for (int r = 0; r < 4; ++r) {
            float sm = 0.f;
#pragma unroll
            for (int nt = 0; nt < 8; ++nt) {
                const float a = fmaxf(acc[mt][nt][r] + bcol[nt], 0.f);
                acc[mt][nt][r] = __expf(a - SMAX_SHIFT);
                sm += acc[mt][nt][r];
            }
            sm += __shfl_xor(sm, 1);
            sm += __shfl_xor(sm, 2);
            sm += __shfl_xor(sm, 4);
            sm += __shfl_xor(sm, 8);
            rs[r] = 1.f / sm;
        }
#pragma unroll
        for (int nt = 0; nt < 8; ++nt) {
            float v = 0.f;
#pragma unroll
            for (int r = 0; r < 4; ++r) {
                const float fv = bfu2f(Fl[(w * 32 + mt * 16 + quad * 4 + r) * 136 + nt * 16 + c16]);
                v += acc[mt][nt][r] * rs[r] * fv;
            }
            v += __shfl_xor(v, 16);
            v += __shfl_xor(v, 32);
            if (lane < 16)
                AGG[(w * 2 + mt) * 136 + nt * 16 + c16] = f2bf(v);   // rows 0..7
        }
    }
    __syncthreads();

    // ======================= fused post: 3 chained GEMMs ====================
    // wave w handles column tiles {w*2, w*2+1}; M=16 (rows 0..7 valid)

    // ---- GEMM1: h2 = relu(agg @ Wg2 + bg2) -> H2 (LDS, A-layout) ----
    {
        const ushortT* GB = wsw + WS_WGT2;
        f32x4 g[2];
#pragma unroll
        for (int j = 0; j < 2; ++j)
#pragma unroll
            for (int r = 0; r < 4; ++r) g[j][r] = 0.f;
#pragma unroll
        for (int ks = 0; ks < 4; ++ks) {
            const bf16x8 a = *(const bf16x8*)&AGG[c16 * 136 + ks * 32 + quad * 8];
#pragma unroll
            for (int j = 0; j < 2; ++j) {
                const bf16x8 b = *(const bf16x8*)&GB[((w * 2 + j) * 16 + c16) * 136 + ks * 32 + quad * 8];
                MFMA16(g[j], a, b);
            }
        }
#pragma unroll
        for (int j = 0; j < 2; ++j) {
            const int col = (w * 2 + j) * 16 + c16;
            const float bias = bg[col];
#pragma unroll
            for (int r = 0; r < 4; ++r)
                H2[(quad * 4 + r) * 136 + col] = f2bf(fmaxf(g[j][r] + bias, 0.f));
        }
    }
    __syncthreads();

    // ---- GEMM2: u = relu(h2 @ Wup + bup), regs ----
    f32x4 u[2];
    {
        const ushortT* UB = wsw + WS_WUPT;
#pragma unroll
        for (int j = 0; j < 2; ++j)
#pragma unroll
            for (int r = 0; r < 4; ++r) u[j][r] = 0.f;
#pragma unroll
        for (int ks = 0; ks < 4; ++ks) {
            const bf16x8 a = *(const bf16x8*)&H2[c16 * 136 + ks * 32 + quad * 8];
#pragma unroll
            for (int j = 0; j < 2; ++j) {
                const bf16x8 b = *(const bf16x8*)&UB[((w * 2 + j) * 16 + c16) * 136 + ks * 32 + quad * 8];
                MFMA16(u[j], a, b);
            }
        }
#pragma unroll
        for (int j = 0; j < 2; ++j) {
            const float bias = bup[(w * 2 + j) * 16 + c16];
#pragma unroll
            for (int r = 0; r < 4; ++r) u[j][r] = fmaxf(u[j][r] + bias, 0.f);
        }
    }

    // ---- GEMM3: sc = relu(x2 @ Wsc + bsc); out = u + sc ----
    {
        const ushortT* SB = wsw + WS_WSCT;   // [128][72]
        // A-frag direct from global x: lane = node c16 (&7: rows 8..15 mirror,
        // discarded), k = ks*32 + quad*8 + j
        const int pinx = idx1[idx2[d0 + (c16 & 7)]];
        const float* xrow = &x[(size_t)pinx * 64];
        f32x4 s[2];
#pragma unroll
        for (int j = 0; j < 2; ++j)
#pragma unroll
            for (int r = 0; r < 4; ++r) s[j][r] = 0.f;
#pragma unroll
        for (int ks = 0; ks < 2; ++ks) {
            const float4 v0 = *reinterpret_cast<const float4*>(xrow + ks * 32 + quad * 8);
            const float4 v1 = *reinterpret_cast<const float4*>(xrow + ks * 32 + quad * 8 + 4);
            union { bf16x8 v; unsigned u[4]; } a;
            a.u[0] = pack2(v0.x, v0.y); a.u[1] = pack2(v0.z, v0.w);
            a.u[2] = pack2(v1.x, v1.y); a.u[3] = pack2(v1.z, v1.w);
#pragma unroll
            for (int j = 0; j < 2; ++j) {
                const bf16x8 b = *(const bf16x8*)&SB[((w * 2 + j) * 16 + c16) * 72 + ks * 32 + quad * 8];
                MFMA16(s[j], a.v, b);
            }
        }
        if (quad < 2) {      // rows 0..7 valid
#pragma unroll
            for (int j = 0; j < 2; ++j) {
                const int col = (w * 2 + j) * 16 + c16;
                const float bias = bsc[col];
#pragma unroll
                for (int r = 0; r < 4; ++r) {
                    const float sc = fmaxf(s[j][r] + bias, 0.f);
                    const int row = d0 + quad * 4 + r;
                    out[(size_t)row * 128 + col] = u[j][r] + sc;  // both >=0
                }
            }
        }
    }
}

extern "C" void kernel_launch(void* const* d_in, const int* in_sizes, int n_in,
                              void* d_out, int out_size, void* d_ws, size_t ws_size,
                              hipStream_t stream)
{
    const float* x      = (const float*)d_in[0];
    const float* pos    = (const float*)d_in[1];
    const float* W_down = (const float*)d_in[2];
    const float* b_down = (const float*)d_in[3];
    const float* W_pp1  = (const float*)d_in[4];
    const float* b_pp1  = (const float*)d_in[5];
    const float* W_att1 = (const float*)d_in[6];
    const float* b_att1 = (const float*)d_in[7];
    const float* W_g1   = (const float*)d_in[8];
    const float* b_g1   = (const float*)d_in[9];
    const float* W_pp2  = (const float*)d_in[10];
    const float* b_pp2  = (const float*)d_in[11];
    const float* W_att2 = (const float*)d_in[12];
    const float* b_att2 = (const float*)d_in[13];
    const float* W_g2   = (const float*)d_in[14];
    const float* b_g2   = (const float*)d_in[15];
    const float* W_up   = (const float*)d_in[16];
    const float* b_up   = (const float*)d_in[17];
    const float* W_sc   = (const float*)d_in[18];
    const float* b_sc   = (const float*)d_in[19];
    const int* idx1 = (const int*)d_in[20];
    const int* idx2 = (const int*)d_in[21];
    const int* src1 = (const int*)d_in[22];
    const int* src2 = (const int*)d_in[24];

    ushortT* wsw = (ushortT*)d_ws;
    ushortT* h0w = wsw + WS_H0;
    ushortT* h1w = wsw + WS_H1;

    k_down  <<<512 + 68, 256, 0, stream>>>(x, W_down, b_down,
                                           W_att1, W_g1, W_att2, W_g2, W_up, W_sc,
                                           wsw, h0w);
    k_conv1 <<<NN1 / 8, 256, 0, stream>>>(h0w, pos, idx1, src1,
                                          W_pp1, b_pp1, wsw, b_att1, b_g1, h1w);
    k_conv2f<<<NN2 / 8, 256, 0, stream>>>(h1w, pos, x, idx1, idx2, src2,
                                          W_pp2, b_pp2, wsw, b_att2,
                                          b_g2, b_up, b_sc, (float*)d_out);
}